// Round 11
// baseline (360.929 us; speedup 1.0000x reference)
//
#include <hip/hip_runtime.h>
#include <hip/hip_fp16.h>

#define DI __device__ __forceinline__

constexpr int NGRAPH = 500;
constexpr int EDGES  = 800000;
constexpr int NBIN   = NGRAPH * 16;   // (graph, relation)

// ---- workspace layout (4-byte units) ----
constexpr size_t WI_HIST = 0;                    // [8000]
constexpr size_t WI_OFF  = WI_HIST + NBIN;       // [8001]
constexpr size_t WI_CURS = WI_OFF + NBIN + 1;    // [8000]
constexpr size_t WI_META = WI_CURS + NBIN;       // [E]
constexpr size_t WI_ORIG = WI_META + EDGES;      // [E]
constexpr size_t WF_PREP = WI_ORIG + EDGES;      // 656 floats
constexpr size_t WF_WFRAG = WF_PREP + 672;       // uint4[5120]: W-frags[4096] + We-frags[1024]

// ---- LDS layout (bytes), total 141872 -> 1 block/CU ----
constexpr int S_H   = 0;        // f16 h[100][40]   (cols 0..31 used)
constexpr int S_HP  = 8000;     // f16 hp[100][128] (col c -> d=c>>2, h=c&3), XOR-swizzled
constexpr int S_U   = 33600;    // f16 U[100][516]  (16 rels x 32 dims + pad)
constexpr int S_EH  = 136800;   // f32[100][4]
constexpr int S_ET  = 138400;   // f32[100][4]
constexpr int S_DEN = 140000;   // f32[100][4]
constexpr int S_RA  = 141600;   // f32[16][4]
constexpr int S_ESG = 141856;   // f32[4]
constexpr int S_TOTAL = 141872;
constexpr int UROW = 516;       // f16 elems per U row (1032 B; stride 8 mod 128 -> banks spread)

typedef _Float16 f16x8 __attribute__((ext_vector_type(8)));
typedef float f32x4 __attribute__((ext_vector_type(4)));

DI float lrelu(float x) { return x >= 0.f ? x : 0.2f * x; }
DI f16x8 u4_to_f16x8(uint4 u) { f16x8 r; __builtin_memcpy(&r, &u, 16); return r; }
DI f16x8 two_u2(uint2 a, uint2 b) { return u4_to_f16x8(make_uint4(a.x, a.y, b.x, b.y)); }

// hp swizzle: half-index for (node n, col c); XOR bits 3..5 with n&7 (16B granularity)
DI int hpIdx(int n, int c) { return n * 128 + (c ^ ((n & 7) << 3)); }

// packed f16 LDS atomic add (ds_pk_add_f16). No "memory" clobber: independent of all
// surrounding loads (hp region reads); __syncthreads() drains lgkmcnt before any U read.
DI void ldsPkAddF16(__half* p, float v0, float v1) {
    __half2 hv = __floats2half2_rn(v0, v1);
    unsigned uv; __builtin_memcpy(&uv, &hv, 4);
    unsigned addr = (unsigned)(unsigned long long)p;
    asm volatile("ds_pk_add_f16 %0, %1" :: "v"(addr), "v"(uv));
}

// ---------------- binning: (graph, relation) bins, ~100 edges/bin ----------------
__global__ void k_hist(const int* __restrict__ dst, const int* __restrict__ rt,
                       int* __restrict__ hist) {
    int e = blockIdx.x * 256 + threadIdx.x;
    if (e >= EDGES) return;
    unsigned g = (unsigned)dst[e] / 100u;
    atomicAdd(&hist[g * 16 + rt[e]], 1);
}

__global__ void k_scan(const int* __restrict__ hist, int* __restrict__ off,
                       int* __restrict__ curs) {
    __shared__ int sc[1024];
    int t = threadIdx.x;
    int v[8]; int s = 0;
    #pragma unroll
    for (int i = 0; i < 8; ++i) { int b = t*8 + i; v[i] = (b < NBIN) ? hist[b] : 0; s += v[i]; }
    sc[t] = s; __syncthreads();
    for (int o = 1; o < 1024; o <<= 1) {
        int a = (t >= o) ? sc[t - o] : 0;
        __syncthreads();
        sc[t] += a;
        __syncthreads();
    }
    int run = sc[t] - s;
    #pragma unroll
    for (int i = 0; i < 8; ++i) {
        int b = t*8 + i;
        if (b < NBIN) { off[b] = run; curs[b] = run; }
        run += v[i];
    }
    if (t == 0) off[NBIN] = EDGES;
}

__global__ void k_scatter(const int* __restrict__ src, const int* __restrict__ dst,
                          const int* __restrict__ rt, int* __restrict__ curs,
                          int* __restrict__ meta, int* __restrict__ orig) {
    int e = blockIdx.x * 256 + threadIdx.x;
    if (e >= EDGES) return;
    int s = src[e], d = dst[e], r = rt[e];
    int g = (unsigned)d / 100u;
    int pos = atomicAdd(&curs[g * 16 + r], 1);
    meta[pos] = (s - g * 100) | ((d - g * 100) << 7) | (r << 14);
    orig[pos] = e;
}

// ---------------- setup: prep folds + f16 MFMA fragments ----------------
__global__ void k_setup(const float* __restrict__ rel_table, const float* __restrict__ Wr,
                        const float* __restrict__ br, const float* __restrict__ We,
                        const float* __restrict__ be, const float* __restrict__ attn_r,
                        const float* __restrict__ attn_rs, const float* __restrict__ attn_s,
                        const float* __restrict__ W, float* __restrict__ prep,
                        uint4* __restrict__ wf) {
    __shared__ float wra[2][32][4];
    __shared__ float sbias[2][3][4];
    int b = blockIdx.x, t = threadIdx.x;
    if (b == 0) {
        {
            int l = t >> 7, k = (t >> 2) & 31, h = t & 3;
            float a = 0.f, bb = 0.f, c = 0.f;
            for (int d2 = 0; d2 < 32; ++d2) {
                float w1 = Wr[(size_t)(l*32 + k)*128 + h*32 + d2];
                float w2 = We[(size_t)(l*32 + k)*128 + h*32 + d2];
                a  += w1 * attn_r [l*128 + h*32 + d2];
                bb += w1 * attn_rs[l*128 + h*32 + d2];
                c  += w2 * attn_s [l*128 + h*32 + d2];
            }
            wra[l][k][h] = a;
            prep[128 + (l*32 + k)*4 + h] = bb;
            prep[384 + (l*32 + k)*4 + h] = c;
        }
        if (t < 24) {
            int l = t / 12, which = (t % 12) / 4, h = t % 4;
            const float* bp = (which == 2) ? be : br;
            const float* ap = (which == 0) ? attn_r : (which == 1 ? attn_rs : attn_s);
            float s = 0.f;
            for (int d2 = 0; d2 < 32; ++d2) s += bp[l*128 + h*32 + d2] * ap[l*128 + h*32 + d2];
            sbias[l][which][h] = s;
        }
        __syncthreads();
        if (t < 128) {
            int l = t >> 6, r = (t >> 2) & 15, h = t & 3;
            float s = sbias[l][0][h];
            for (int k = 0; k < 32; ++k) s += rel_table[r*32 + k] * wra[l][k][h];
            prep[(l*16 + r)*4 + h] = s;
        }
        if (t < 8) {
            int l = t >> 2, h = t & 3;
            prep[640 + l*4 + h] = sbias[l][1][h];
            prep[648 + l*4 + h] = sbias[l][2][h];
        }
    } else if (b <= 16) {
        // W fragments (f16): wf[((l*16+rel)*2+Nt)*64 + ln]
        int fi = (b - 1) * 256 + t;
        int ln = fi & 63, Nt = (fi >> 6) & 1, rel = (fi >> 7) & 15, l = fi >> 11;
        int j = Nt*16 + (ln & 15), k0 = (ln >> 4) << 3;
        unsigned short fr[8];
        #pragma unroll
        for (int i = 0; i < 8; ++i) {
            __half hv = __float2half(W[(((size_t)l*16 + rel)*32 + k0 + i)*32 + j]);
            __builtin_memcpy(&fr[i], &hv, 2);
        }
        uint4 o;
        o.x = fr[0] | ((unsigned)fr[1] << 16);
        o.y = fr[2] | ((unsigned)fr[3] << 16);
        o.z = fr[4] | ((unsigned)fr[5] << 16);
        o.w = fr[6] | ((unsigned)fr[7] << 16);
        wf[fi] = o;
    } else {
        // We fragments (f16, column-permuted): col c -> phys (c&3)*32+(c>>2)
        int fi = (b - 17) * 256 + t;
        int ln = fi & 63, Nt = (fi >> 6) & 7, l = fi >> 9;
        int c = Nt*16 + (ln & 15);
        int phys = (c & 3)*32 + (c >> 2);
        int k0 = (ln >> 4) << 3;
        unsigned short fr[8];
        #pragma unroll
        for (int i = 0; i < 8; ++i) {
            __half hv = __float2half(We[(size_t)l*4096 + (k0 + i)*128 + phys]);
            __builtin_memcpy(&fr[i], &hv, 2);
        }
        uint4 o;
        o.x = fr[0] | ((unsigned)fr[1] << 16);
        o.y = fr[2] | ((unsigned)fr[3] << 16);
        o.z = fr[4] | ((unsigned)fr[5] << 16);
        o.w = fr[6] | ((unsigned)fr[7] << 16);
        wf[4096 + fi] = o;
    }
}

// ---------------- fused per-graph forward (single-pass scatter, 4 barriers/layer) ----------------
__global__ void __launch_bounds__(512, 2)
k_fused(const float* __restrict__ state, const float* __restrict__ rw,
        const float* __restrict__ code_emb, const float* __restrict__ h_bias,
        const float* __restrict__ be, const float* __restrict__ attn_h,
        const float* __restrict__ attn_t, const int* __restrict__ node_ids,
        const int* __restrict__ off, const int* __restrict__ meta,
        const int* __restrict__ orig, const float* __restrict__ prep,
        const uint4* __restrict__ wf,
        float* __restrict__ xout, float* __restrict__ relOut, float* __restrict__ edgeOut) {
    extern __shared__ char smem[];
    __half* hH  = (__half*)(smem + S_H);
    __half* hpH = (__half*)(smem + S_HP);
    __half* Uh  = (__half*)(smem + S_U);
    float* ehp  = (float*)(smem + S_EH);
    float* etp  = (float*)(smem + S_ET);
    float* denp = (float*)(smem + S_DEN);
    float* rap  = (float*)(smem + S_RA);
    float* esgp = (float*)(smem + S_ESG);
    const uint4* wfe = wf + 4096;

    const int g = blockIdx.x;
    const int t = threadIdx.x;
    const int lane = t & 63, w = t >> 6;
    const int ln15 = lane & 15, q = lane >> 4, q8 = q << 3;
    const int MtA = w % 7, NtA = w / 7;
    const int MtB = (w + 8) % 7, NtB = (w + 8) / 7;
    const bool hasB = (w < 6);
    const int colc = w * 16 + ln15;
    const int physc = (colc & 3) * 32 + (colc >> 2);

    const int gbase = off[g * 16];
    const int ecnt  = off[g * 16 + 16] - gbase;

    // P0: h0 = code_emb[node_ids] (f16, [100][40]); zero eh/et/den
    for (int i = t; i < 1600; i += 512) {
        int n = i >> 4, dp = i & 15;
        int id = node_ids[g * 100 + n];
        float2 v = *(const float2*)&code_emb[(size_t)id * 32 + dp * 2];
        *(__half2*)&hH[n * 40 + dp * 2] = __floats2half2_rn(v.x, v.y);
    }
    for (int i = t; i < 300; i += 512) ((uint4*)(smem + S_EH))[i] = make_uint4(0, 0, 0, 0);

    // edge meta -> registers (4 slots per thread; 2048 >= max edges/graph)
    int em[4];
    #pragma unroll
    for (int k = 0; k < 4; ++k) {
        int e = t + k * 512;
        em[k] = (e < ecnt) ? meta[gbase + e] : -1;
    }

    // scatter ALL edges: coefficient from LDS state, 16 packed adds into U
    auto scatterAll = [&](bool writeAtt) {
        float4 esg4 = *(const float4*)esgp;
        #pragma unroll
        for (int k = 0; k < 4; ++k) {
            int m = em[k];
            if (m >= 0) {
                int s = m & 127, d = (m >> 7) & 127, r = (m >> 14) & 15;
                int cb = r * 32;
                int sw = (s & 7) << 3;
                float4 eh4 = *(const float4*)&ehp[s * 4];
                float4 et4 = *(const float4*)&etp[d * 4];
                float4 dn  = *(const float4*)&denp[d * 4];
                float4 r4  = *(const float4*)&rap[r * 4];
                float a0 = __expf(lrelu(eh4.x + et4.x + esg4.x)) / dn.x;
                float a1 = __expf(lrelu(eh4.y + et4.y + esg4.y)) / dn.y;
                float a2 = __expf(lrelu(eh4.z + et4.z + esg4.z)) / dn.z;
                float a3 = __expf(lrelu(eh4.w + et4.w + esg4.w)) / dn.w;
                if (writeAtt) {
                    int oe = orig[gbase + t + k * 512];
                    *(float4*)&edgeOut[(size_t)oe * 4] = make_float4(a0, a1, a2, a3);
                    *(float4*)&relOut[(size_t)oe * 4] = r4;
                }
                float c0 = a0 * r4.x, c1 = a1 * r4.y, c2 = a2 * r4.z, c3 = a3 * r4.w;
                #pragma unroll 8
                for (int db = 0; db < 16; ++db) {
                    uint4 hv = *(const uint4*)&hpH[s * 128 + ((db * 8) ^ sw)];
                    float2 f01 = __half22float2(*(const __half2*)&hv.x);
                    float2 f23 = __half22float2(*(const __half2*)&hv.y);
                    float2 f45 = __half22float2(*(const __half2*)&hv.z);
                    float2 f67 = __half22float2(*(const __half2*)&hv.w);
                    float v0 = c0*f01.x + c1*f01.y + c2*f23.x + c3*f23.y;
                    float v1 = c0*f45.x + c1*f45.y + c2*f67.x + c3*f67.y;
                    ldsPkAddF16(Uh + d * UROW + cb + db * 2, v0, v1);
                }
            }
        }
    };

    for (int l = 0; l < 2; ++l) {
        __syncthreads();   // B0: h ready, eh/et/den zeroed, U free

        // ---- X1: zero U; P2-MFMA (hp = h@We + be) + eh/et epilogue; P1 rel-att ----
        for (int i = t; i < 6450; i += 512) ((uint4*)(smem + S_U))[i] = make_uint4(0, 0, 0, 0);
        {
            uint4 bwe = wfe[(l * 8 + w) * 64 + lane];
            f16x8 bw = u4_to_f16x8(bwe);
            float beC = be[l * 128 + physc];
            float ahC = attn_h[l * 128 + physc];
            float atC = attn_t[l * 128 + physc];
            f32x4 z = {0.f, 0.f, 0.f, 0.f};
            const __half* hr0 = hH + ln15 * 40 + q8;
            f32x4 pcur = __builtin_amdgcn_mfma_f32_16x16x32_f16(
                two_u2(*(const uint2*)hr0, *(const uint2*)(hr0 + 4)), bw, z, 0, 0, 0);
            #pragma unroll
            for (int Mt = 0; Mt < 7; ++Mt) {
                f32x4 pnxt;
                if (Mt < 6) {
                    const __half* hr = hH + ((Mt + 1) * 16 + ln15) * 40 + q8;
                    pnxt = __builtin_amdgcn_mfma_f32_16x16x32_f16(
                        two_u2(*(const uint2*)hr, *(const uint2*)(hr + 4)), bw, z, 0, 0, 0);
                }
                #pragma unroll
                for (int i = 0; i < 4; ++i) {
                    int n = Mt * 16 + q * 4 + i;
                    float hv = pcur[i] + beC;
                    bool ok = (n < 100);
                    if (ok) hpH[hpIdx(n, colc)] = __float2half(hv);
                    float veh = ok ? hv * ahC : 0.f;
                    float vet = ok ? hv * atC : 0.f;
                    veh += __shfl_xor(veh, 4); vet += __shfl_xor(vet, 4);
                    veh += __shfl_xor(veh, 8); vet += __shfl_xor(vet, 8);
                    if (ok && (ln15 & 12) == 0) {
                        atomicAdd(&ehp[n * 4 + (ln15 & 3)], veh);
                        atomicAdd(&etp[n * 4 + (ln15 & 3)], vet);
                    }
                }
                pcur = pnxt;
            }
        }
        {   // P1: relation attention (all waves redundantly)
            int k32 = lane & 31;
            float sG = state[g * 32 + k32];
            float4 frs = *(const float4*)&prep[128 + l * 128 + k32 * 4];
            float4 fes = *(const float4*)&prep[384 + l * 128 + k32 * 4];
            float p0 = sG * frs.x, p1 = sG * frs.y, p2 = sG * frs.z, p3 = sG * frs.w;
            float q0 = sG * fes.x, q1 = sG * fes.y, q2 = sG * fes.z, q3 = sG * fes.w;
            #pragma unroll
            for (int m = 1; m < 32; m <<= 1) {
                p0 += __shfl_xor(p0, m); p1 += __shfl_xor(p1, m);
                p2 += __shfl_xor(p2, m); p3 += __shfl_xor(p3, m);
                q0 += __shfl_xor(q0, m); q1 += __shfl_xor(q1, m);
                q2 += __shfl_xor(q2, m); q3 += __shfl_xor(q3, m);
            }
            int h = lane & 3;
            float esh  = (h & 2) ? ((h & 1) ? p3 : p2) : ((h & 1) ? p1 : p0);
            float esgh = (h & 2) ? ((h & 1) ? q3 : q2) : ((h & 1) ? q1 : q0);
            esh  += prep[640 + l * 4 + h];
            esgh += prep[648 + l * 4 + h];
            if (lane < 4) esgp[lane] = esgh;
            float er = prep[l * 64 + lane];
            float ex = __expf(lrelu(er + esh));
            float s = ex;
            s += __shfl_xor(s, 4); s += __shfl_xor(s, 8);
            s += __shfl_xor(s, 16); s += __shfl_xor(s, 32);
            rap[lane] = ex / s;
        }
        __syncthreads();   // B1: hp/eh/et/rap/esg ready, U zeroed

        // ---- X2: edge exp -> den ----
        {
            float4 esg4 = *(const float4*)esgp;
            #pragma unroll
            for (int k = 0; k < 4; ++k) {
                int m = em[k];
                if (m >= 0) {
                    int s = m & 127, d = (m >> 7) & 127;
                    float4 eh4 = *(const float4*)&ehp[s * 4];
                    float4 et4 = *(const float4*)&etp[d * 4];
                    atomicAdd(&denp[d * 4 + 0], __expf(lrelu(eh4.x + et4.x + esg4.x)));
                    atomicAdd(&denp[d * 4 + 1], __expf(lrelu(eh4.y + et4.y + esg4.y)));
                    atomicAdd(&denp[d * 4 + 2], __expf(lrelu(eh4.z + et4.z + esg4.z)));
                    atomicAdd(&denp[d * 4 + 3], __expf(lrelu(eh4.w + et4.w + esg4.w)));
                }
            }
        }
        __syncthreads();   // B2: den final

        scatterAll(l == 1);
        __syncthreads();   // B3: U complete

        // ---- P7: 16-relation MFMA chain (B-frags loaded just-in-time from L2) ----
        f32x4 accA = {0.f, 0.f, 0.f, 0.f};
        f32x4 accB = {0.f, 0.f, 0.f, 0.f};
        #pragma unroll 4
        for (int rel = 0; rel < 16; ++rel) {
            {
                uint4 bAu = wf[((l * 16 + rel) * 2 + NtA) * 64 + lane];
                const __half* up = Uh + (MtA * 16 + ln15) * UROW + rel * 32 + q8;
                f16x8 af = two_u2(*(const uint2*)up, *(const uint2*)(up + 4));
                accA = __builtin_amdgcn_mfma_f32_16x16x32_f16(af, u4_to_f16x8(bAu), accA, 0, 0, 0);
            }
            if (hasB) {
                uint4 bBu = wf[((l * 16 + rel) * 2 + NtB) * 64 + lane];
                const __half* up = Uh + (MtB * 16 + ln15) * UROW + rel * 32 + q8;
                f16x8 af = two_u2(*(const uint2*)up, *(const uint2*)(up + 4));
                accB = __builtin_amdgcn_mfma_f32_16x16x32_f16(af, u4_to_f16x8(bBu), accB, 0, 0, 0);
            }
        }
        // P8: h = relu(0.5*(agg+bias) + 0.5*h); zero eh/et/den for next layer
        if (l == 0)
            for (int i = t; i < 300; i += 512) ((uint4*)(smem + S_EH))[i] = make_uint4(0, 0, 0, 0);
        {
            int dcol = NtA * 16 + ln15;
            float bias = h_bias[l * 32 + dcol];
            #pragma unroll
            for (int i = 0; i < 4; ++i) {
                int n = MtA * 16 + q * 4 + i;
                if (n < 100) {
                    float hold = __half2float(hH[n * 40 + dcol]);
                    float hn = fmaxf(0.f, 0.5f * (accA[i] + bias) + 0.5f * hold);
                    hH[n * 40 + dcol] = __float2half(hn);
                }
            }
        }
        if (hasB) {
            int dcol = NtB * 16 + ln15;
            float bias = h_bias[l * 32 + dcol];
            #pragma unroll
            for (int i = 0; i < 4; ++i) {
                int n = MtB * 16 + q * 4 + i;
                if (n < 100) {
                    float hold = __half2float(hH[n * 40 + dcol]);
                    float hn = fmaxf(0.f, 0.5f * (accB[i] + bias) + 0.5f * hold);
                    hH[n * 40 + dcol] = __float2half(hn);
                }
            }
        }
    }
    __syncthreads();   // h final

    // P9: readout x[g] = sum_n h[n] * rw[n]   (red buffer reuses U region)
    float* redp = (float*)(smem + S_U);
    {
        int part = t >> 5, d = t & 31;
        float acc = 0.f;
        for (int n = part; n < 100; n += 16)
            acc += __half2float(hH[n * 40 + d]) * rw[g * 100 + n];
        redp[part * 32 + d] = acc;
    }
    __syncthreads();
    if (t < 32) {
        float s = 0.f;
        #pragma unroll
        for (int p = 0; p < 16; ++p) s += redp[p * 32 + t];
        xout[g * 32 + t] = s;
    }
}

extern "C" void kernel_launch(void* const* d_in, const int* in_sizes, int n_in,
                              void* d_out, int out_size, void* d_ws, size_t ws_size,
                              hipStream_t stream) {
    const float* state     = (const float*)d_in[0];
    const float* rw        = (const float*)d_in[1];
    const float* code_emb  = (const float*)d_in[2];
    const float* rel_table = (const float*)d_in[3];
    const float* W         = (const float*)d_in[4];
    const float* h_bias    = (const float*)d_in[5];
    const float* Wr        = (const float*)d_in[6];
    const float* br        = (const float*)d_in[7];
    const float* We        = (const float*)d_in[8];
    const float* be        = (const float*)d_in[9];
    const float* attn_h    = (const float*)d_in[10];
    const float* attn_t    = (const float*)d_in[11];
    const float* attn_s    = (const float*)d_in[12];
    const float* attn_r    = (const float*)d_in[13];
    const float* attn_rs   = (const float*)d_in[14];
    const int* node_ids    = (const int*)d_in[15];
    const int* src         = (const int*)d_in[16];
    const int* dst         = (const int*)d_in[17];
    const int* rtype       = (const int*)d_in[18];

    float* out = (float*)d_out;
    float* xout = out;
    float* relOut = out + (size_t)NGRAPH * 32;
    float* edgeOut = relOut + (size_t)EDGES * 4;

    int* wsi = (int*)d_ws;
    float* wsf = (float*)d_ws;
    int* hist = wsi + WI_HIST;
    int* off  = wsi + WI_OFF;
    int* curs = wsi + WI_CURS;
    int* meta = wsi + WI_META;
    int* orig = wsi + WI_ORIG;
    float* prep = wsf + WF_PREP;
    uint4* wfrag = (uint4*)(wsf + WF_WFRAG);

    (void)hipMemsetAsync(hist, 0, NBIN * sizeof(int), stream);
    k_hist<<<(EDGES + 255) / 256, 256, 0, stream>>>(dst, rtype, hist);
    k_scan<<<1, 1024, 0, stream>>>(hist, off, curs);
    k_scatter<<<(EDGES + 255) / 256, 256, 0, stream>>>(src, dst, rtype, curs, meta, orig);
    k_setup<<<21, 256, 0, stream>>>(rel_table, Wr, br, We, be, attn_r, attn_rs, attn_s,
                                    W, prep, wfrag);

    (void)hipFuncSetAttribute((const void*)k_fused, hipFuncAttributeMaxDynamicSharedMemorySize, S_TOTAL);
    k_fused<<<NGRAPH, 512, S_TOTAL, stream>>>(state, rw, code_emb, h_bias, be,
                                              attn_h, attn_t, node_ids, off, meta, orig,
                                              prep, wfrag, xout, relOut, edgeOut);
}

// Round 12
// 355.588 us; speedup vs baseline: 1.0150x; 1.0150x over previous
//
#include <hip/hip_runtime.h>
#include <hip/hip_fp16.h>

#define DI __device__ __forceinline__

constexpr int NGRAPH = 500;
constexpr int EDGES  = 800000;
constexpr int NBIN   = NGRAPH * 16;   // (graph, relation)

// ---- workspace layout (4-byte units) ----
constexpr size_t WI_HIST = 0;                    // [8000]
constexpr size_t WI_OFF  = WI_HIST + NBIN;       // [8001]
constexpr size_t WI_CURS = WI_OFF + NBIN + 1;    // [8000]
constexpr size_t WI_META = WI_CURS + NBIN;       // [E]
constexpr size_t WI_ORIG = WI_META + EDGES;      // [E]
constexpr size_t WF_PREP = WI_ORIG + EDGES;      // 656 floats
constexpr size_t WF_WFRAG = WF_PREP + 672;       // uint4[5120]: W-frags[4096] + We-frags[1024]

// ---- LDS layout (bytes), total 141872 -> 1 block/CU ----
constexpr int S_H   = 0;        // f16 h[100][40]   (cols 0..31 used)
constexpr int S_HP  = 8000;     // f16 hp[100][128] (col c -> d=c>>2, h=c&3), XOR-swizzled
constexpr int S_U   = 33600;    // f16 U[100][516]  (16 rels x 32 dims + pad)
constexpr int S_EH  = 136800;   // f32[100][4]
constexpr int S_ET  = 138400;   // f32[100][4]
constexpr int S_DEN = 140000;   // f32[100][4]
constexpr int S_RA  = 141600;   // f32[16][4]
constexpr int S_ESG = 141856;   // f32[4]
constexpr int S_TOTAL = 141872;
constexpr int UROW = 516;       // f16 elems per U row

typedef _Float16 f16x8 __attribute__((ext_vector_type(8)));
typedef float f32x4 __attribute__((ext_vector_type(4)));

DI float lrelu(float x) { return x >= 0.f ? x : 0.2f * x; }
DI f16x8 u4_to_f16x8(uint4 u) { f16x8 r; __builtin_memcpy(&r, &u, 16); return r; }
DI f16x8 two_u2(uint2 a, uint2 b) { return u4_to_f16x8(make_uint4(a.x, a.y, b.x, b.y)); }

// hp swizzle: half-index for (node n, col c); XOR bits 3..5 with n&7 (16B granularity)
DI int hpIdx(int n, int c) { return n * 128 + (c ^ ((n & 7) << 3)); }

// packed f16 LDS atomic add (ds_pk_add_f16); __syncthreads() orders U reads after.
DI void ldsPkAddF16(__half* p, float v0, float v1) {
    __half2 hv = __floats2half2_rn(v0, v1);
    unsigned uv; __builtin_memcpy(&uv, &hv, 4);
    unsigned addr = (unsigned)(unsigned long long)p;
    asm volatile("ds_pk_add_f16 %0, %1" :: "v"(addr), "v"(uv));
}

// ---------------- binning: (graph, relation) bins, ~100 edges/bin ----------------
__global__ void k_hist(const int* __restrict__ dst, const int* __restrict__ rt,
                       int* __restrict__ hist) {
    int e = blockIdx.x * 256 + threadIdx.x;
    if (e >= EDGES) return;
    unsigned g = (unsigned)dst[e] / 100u;
    atomicAdd(&hist[g * 16 + rt[e]], 1);
}

__global__ void k_scan(const int* __restrict__ hist, int* __restrict__ off,
                       int* __restrict__ curs) {
    __shared__ int sc[1024];
    int t = threadIdx.x;
    int v[8]; int s = 0;
    #pragma unroll
    for (int i = 0; i < 8; ++i) { int b = t*8 + i; v[i] = (b < NBIN) ? hist[b] : 0; s += v[i]; }
    sc[t] = s; __syncthreads();
    for (int o = 1; o < 1024; o <<= 1) {
        int a = (t >= o) ? sc[t - o] : 0;
        __syncthreads();
        sc[t] += a;
        __syncthreads();
    }
    int run = sc[t] - s;
    #pragma unroll
    for (int i = 0; i < 8; ++i) {
        int b = t*8 + i;
        if (b < NBIN) { off[b] = run; curs[b] = run; }
        run += v[i];
    }
    if (t == 0) off[NBIN] = EDGES;
}

__global__ void k_scatter(const int* __restrict__ src, const int* __restrict__ dst,
                          const int* __restrict__ rt, int* __restrict__ curs,
                          int* __restrict__ meta, int* __restrict__ orig) {
    int e = blockIdx.x * 256 + threadIdx.x;
    if (e >= EDGES) return;
    int s = src[e], d = dst[e], r = rt[e];
    int g = (unsigned)d / 100u;
    int pos = atomicAdd(&curs[g * 16 + r], 1);
    meta[pos] = (s - g * 100) | ((d - g * 100) << 7) | (r << 14);
    orig[pos] = e;
}

// ---------------- setup: prep folds + f16 MFMA fragments ----------------
__global__ void k_setup(const float* __restrict__ rel_table, const float* __restrict__ Wr,
                        const float* __restrict__ br, const float* __restrict__ We,
                        const float* __restrict__ be, const float* __restrict__ attn_r,
                        const float* __restrict__ attn_rs, const float* __restrict__ attn_s,
                        const float* __restrict__ W, float* __restrict__ prep,
                        uint4* __restrict__ wf) {
    __shared__ float wra[2][32][4];
    __shared__ float sbias[2][3][4];
    int b = blockIdx.x, t = threadIdx.x;
    if (b == 0) {
        {
            int l = t >> 7, k = (t >> 2) & 31, h = t & 3;
            float a = 0.f, bb = 0.f, c = 0.f;
            for (int d2 = 0; d2 < 32; ++d2) {
                float w1 = Wr[(size_t)(l*32 + k)*128 + h*32 + d2];
                float w2 = We[(size_t)(l*32 + k)*128 + h*32 + d2];
                a  += w1 * attn_r [l*128 + h*32 + d2];
                bb += w1 * attn_rs[l*128 + h*32 + d2];
                c  += w2 * attn_s [l*128 + h*32 + d2];
            }
            wra[l][k][h] = a;
            prep[128 + (l*32 + k)*4 + h] = bb;
            prep[384 + (l*32 + k)*4 + h] = c;
        }
        if (t < 24) {
            int l = t / 12, which = (t % 12) / 4, h = t % 4;
            const float* bp = (which == 2) ? be : br;
            const float* ap = (which == 0) ? attn_r : (which == 1 ? attn_rs : attn_s);
            float s = 0.f;
            for (int d2 = 0; d2 < 32; ++d2) s += bp[l*128 + h*32 + d2] * ap[l*128 + h*32 + d2];
            sbias[l][which][h] = s;
        }
        __syncthreads();
        if (t < 128) {
            int l = t >> 6, r = (t >> 2) & 15, h = t & 3;
            float s = sbias[l][0][h];
            for (int k = 0; k < 32; ++k) s += rel_table[r*32 + k] * wra[l][k][h];
            prep[(l*16 + r)*4 + h] = s;
        }
        if (t < 8) {
            int l = t >> 2, h = t & 3;
            prep[640 + l*4 + h] = sbias[l][1][h];
            prep[648 + l*4 + h] = sbias[l][2][h];
        }
    } else if (b <= 16) {
        // W fragments (f16): wf[((l*16+rel)*2+Nt)*64 + ln]
        int fi = (b - 1) * 256 + t;
        int ln = fi & 63, Nt = (fi >> 6) & 1, rel = (fi >> 7) & 15, l = fi >> 11;
        int j = Nt*16 + (ln & 15), k0 = (ln >> 4) << 3;
        unsigned short fr[8];
        #pragma unroll
        for (int i = 0; i < 8; ++i) {
            __half hv = __float2half(W[(((size_t)l*16 + rel)*32 + k0 + i)*32 + j]);
            __builtin_memcpy(&fr[i], &hv, 2);
        }
        uint4 o;
        o.x = fr[0] | ((unsigned)fr[1] << 16);
        o.y = fr[2] | ((unsigned)fr[3] << 16);
        o.z = fr[4] | ((unsigned)fr[5] << 16);
        o.w = fr[6] | ((unsigned)fr[7] << 16);
        wf[fi] = o;
    } else {
        // We fragments (f16, column-permuted): col c -> phys (c&3)*32+(c>>2)
        int fi = (b - 17) * 256 + t;
        int ln = fi & 63, Nt = (fi >> 6) & 7, l = fi >> 9;
        int c = Nt*16 + (ln & 15);
        int phys = (c & 3)*32 + (c >> 2);
        int k0 = (ln >> 4) << 3;
        unsigned short fr[8];
        #pragma unroll
        for (int i = 0; i < 8; ++i) {
            __half hv = __float2half(We[(size_t)l*4096 + (k0 + i)*128 + phys]);
            __builtin_memcpy(&fr[i], &hv, 2);
        }
        uint4 o;
        o.x = fr[0] | ((unsigned)fr[1] << 16);
        o.y = fr[2] | ((unsigned)fr[3] << 16);
        o.z = fr[4] | ((unsigned)fr[5] << 16);
        o.w = fr[6] | ((unsigned)fr[7] << 16);
        wf[4096 + fi] = o;
    }
}

// ---------------- fused per-graph forward: 1024 threads, 16 waves ----------------
__global__ void __launch_bounds__(1024, 1)
k_fused(const float* __restrict__ state, const float* __restrict__ rw,
        const float* __restrict__ code_emb, const float* __restrict__ h_bias,
        const float* __restrict__ be, const float* __restrict__ attn_h,
        const float* __restrict__ attn_t, const int* __restrict__ node_ids,
        const int* __restrict__ off, const int* __restrict__ meta,
        const int* __restrict__ orig, const float* __restrict__ prep,
        const uint4* __restrict__ wf,
        float* __restrict__ xout, float* __restrict__ relOut, float* __restrict__ edgeOut) {
    extern __shared__ char smem[];
    __half* hH  = (__half*)(smem + S_H);
    __half* hpH = (__half*)(smem + S_HP);
    __half* Uh  = (__half*)(smem + S_U);
    float* ehp  = (float*)(smem + S_EH);
    float* etp  = (float*)(smem + S_ET);
    float* denp = (float*)(smem + S_DEN);
    float* rap  = (float*)(smem + S_RA);
    float* esgp = (float*)(smem + S_ESG);
    const uint4* wfe = wf + 4096;

    const int g = blockIdx.x;
    const int t = threadIdx.x;
    const int lane = t & 63, w = t >> 6;          // 16 waves
    const int ln15 = lane & 15, q = lane >> 4, q8 = q << 3;
    // P7/P8 tile (waves 0..13)
    const int MtA = w % 7, NtA = w / 7;
    const bool hasT = (w < 14);
    // X1 column-group: wave pair shares cg; even wave Mt 0..3, odd Mt 4..6
    const int cg = w >> 1;
    const int colc = cg * 16 + ln15;
    const int physc = (colc & 3) * 32 + (colc >> 2);
    const int Mt0 = (w & 1) ? 4 : 0;
    const int Mt1 = (w & 1) ? 7 : 4;

    const int gbase = off[g * 16];
    const int ecnt  = off[g * 16 + 16] - gbase;

    // P0: h0 = code_emb[node_ids] (f16, [100][40]); zero eh/et/den
    for (int i = t; i < 1600; i += 1024) {
        int n = i >> 4, dp = i & 15;
        int id = node_ids[g * 100 + n];
        float2 v = *(const float2*)&code_emb[(size_t)id * 32 + dp * 2];
        *(__half2*)&hH[n * 40 + dp * 2] = __floats2half2_rn(v.x, v.y);
    }
    for (int i = t; i < 300; i += 1024) ((uint4*)(smem + S_EH))[i] = make_uint4(0, 0, 0, 0);

    // edge meta -> registers (2 slots per thread; 2048 >= max edges/graph)
    int em[2];
    #pragma unroll
    for (int k = 0; k < 2; ++k) {
        int e = t + k * 1024;
        em[k] = (e < ecnt) ? meta[gbase + e] : -1;
    }

    // scatter ALL edges: coefficient from LDS state, 16 packed adds into U
    auto scatterAll = [&](bool writeAtt) {
        float4 esg4 = *(const float4*)esgp;
        #pragma unroll
        for (int k = 0; k < 2; ++k) {
            int m = em[k];
            if (m >= 0) {
                int s = m & 127, d = (m >> 7) & 127, r = (m >> 14) & 15;
                int cb = r * 32;
                int sw = (s & 7) << 3;
                float4 eh4 = *(const float4*)&ehp[s * 4];
                float4 et4 = *(const float4*)&etp[d * 4];
                float4 dn  = *(const float4*)&denp[d * 4];
                float4 r4  = *(const float4*)&rap[r * 4];
                float a0 = __expf(lrelu(eh4.x + et4.x + esg4.x)) / dn.x;
                float a1 = __expf(lrelu(eh4.y + et4.y + esg4.y)) / dn.y;
                float a2 = __expf(lrelu(eh4.z + et4.z + esg4.z)) / dn.z;
                float a3 = __expf(lrelu(eh4.w + et4.w + esg4.w)) / dn.w;
                if (writeAtt) {
                    int oe = orig[gbase + t + k * 1024];
                    *(float4*)&edgeOut[(size_t)oe * 4] = make_float4(a0, a1, a2, a3);
                    *(float4*)&relOut[(size_t)oe * 4] = r4;
                }
                float c0 = a0 * r4.x, c1 = a1 * r4.y, c2 = a2 * r4.z, c3 = a3 * r4.w;
                #pragma unroll 4
                for (int db = 0; db < 16; ++db) {
                    uint4 hv = *(const uint4*)&hpH[s * 128 + ((db * 8) ^ sw)];
                    float2 f01 = __half22float2(*(const __half2*)&hv.x);
                    float2 f23 = __half22float2(*(const __half2*)&hv.y);
                    float2 f45 = __half22float2(*(const __half2*)&hv.z);
                    float2 f67 = __half22float2(*(const __half2*)&hv.w);
                    float v0 = c0*f01.x + c1*f01.y + c2*f23.x + c3*f23.y;
                    float v1 = c0*f45.x + c1*f45.y + c2*f67.x + c3*f67.y;
                    ldsPkAddF16(Uh + d * UROW + cb + db * 2, v0, v1);
                }
            }
        }
    };

    for (int l = 0; l < 2; ++l) {
        __syncthreads();   // B0: h ready, eh/et/den zeroed, U free

        // ---- X1: zero U; P2-MFMA (hp = h@We + be) + eh/et epilogue; P1 rel-att ----
        for (int i = t; i < 6450; i += 1024) ((uint4*)(smem + S_U))[i] = make_uint4(0, 0, 0, 0);
        {
            uint4 bwe = wfe[(l * 8 + cg) * 64 + lane];
            f16x8 bw = u4_to_f16x8(bwe);
            float beC = be[l * 128 + physc];
            float ahC = attn_h[l * 128 + physc];
            float atC = attn_t[l * 128 + physc];
            f32x4 z = {0.f, 0.f, 0.f, 0.f};
            for (int Mt = Mt0; Mt < Mt1; ++Mt) {
                const __half* hr = hH + (Mt * 16 + ln15) * 40 + q8;
                f32x4 pc = __builtin_amdgcn_mfma_f32_16x16x32_f16(
                    two_u2(*(const uint2*)hr, *(const uint2*)(hr + 4)), bw, z, 0, 0, 0);
                #pragma unroll
                for (int i = 0; i < 4; ++i) {
                    int n = Mt * 16 + q * 4 + i;
                    float hv = pc[i] + beC;
                    bool ok = (n < 100);
                    if (ok) hpH[hpIdx(n, colc)] = __float2half(hv);
                    float veh = ok ? hv * ahC : 0.f;
                    float vet = ok ? hv * atC : 0.f;
                    veh += __shfl_xor(veh, 4); vet += __shfl_xor(vet, 4);
                    veh += __shfl_xor(veh, 8); vet += __shfl_xor(vet, 8);
                    if (ok && (ln15 & 12) == 0) {
                        atomicAdd(&ehp[n * 4 + (ln15 & 3)], veh);
                        atomicAdd(&etp[n * 4 + (ln15 & 3)], vet);
                    }
                }
            }
        }
        {   // P1: relation attention (all waves redundantly; benign same-value races)
            int k32 = lane & 31;
            float sG = state[g * 32 + k32];
            float4 frs = *(const float4*)&prep[128 + l * 128 + k32 * 4];
            float4 fes = *(const float4*)&prep[384 + l * 128 + k32 * 4];
            float p0 = sG * frs.x, p1 = sG * frs.y, p2 = sG * frs.z, p3 = sG * frs.w;
            float q0 = sG * fes.x, q1 = sG * fes.y, q2 = sG * fes.z, q3 = sG * fes.w;
            #pragma unroll
            for (int m = 1; m < 32; m <<= 1) {
                p0 += __shfl_xor(p0, m); p1 += __shfl_xor(p1, m);
                p2 += __shfl_xor(p2, m); p3 += __shfl_xor(p3, m);
                q0 += __shfl_xor(q0, m); q1 += __shfl_xor(q1, m);
                q2 += __shfl_xor(q2, m); q3 += __shfl_xor(q3, m);
            }
            int h = lane & 3;
            float esh  = (h & 2) ? ((h & 1) ? p3 : p2) : ((h & 1) ? p1 : p0);
            float esgh = (h & 2) ? ((h & 1) ? q3 : q2) : ((h & 1) ? q1 : q0);
            esh  += prep[640 + l * 4 + h];
            esgh += prep[648 + l * 4 + h];
            if (lane < 4) esgp[lane] = esgh;
            float er = prep[l * 64 + lane];
            float ex = __expf(lrelu(er + esh));
            float s = ex;
            s += __shfl_xor(s, 4); s += __shfl_xor(s, 8);
            s += __shfl_xor(s, 16); s += __shfl_xor(s, 32);
            rap[lane] = ex / s;
        }
        __syncthreads();   // B1: hp/eh/et/rap/esg ready, U zeroed

        // ---- X2: edge exp -> den ----
        {
            float4 esg4 = *(const float4*)esgp;
            #pragma unroll
            for (int k = 0; k < 2; ++k) {
                int m = em[k];
                if (m >= 0) {
                    int s = m & 127, d = (m >> 7) & 127;
                    float4 eh4 = *(const float4*)&ehp[s * 4];
                    float4 et4 = *(const float4*)&etp[d * 4];
                    atomicAdd(&denp[d * 4 + 0], __expf(lrelu(eh4.x + et4.x + esg4.x)));
                    atomicAdd(&denp[d * 4 + 1], __expf(lrelu(eh4.y + et4.y + esg4.y)));
                    atomicAdd(&denp[d * 4 + 2], __expf(lrelu(eh4.z + et4.z + esg4.z)));
                    atomicAdd(&denp[d * 4 + 3], __expf(lrelu(eh4.w + et4.w + esg4.w)));
                }
            }
        }
        __syncthreads();   // B2: den final

        scatterAll(l == 1);
        __syncthreads();   // B3: U complete

        // ---- P7: 16-relation MFMA chain (waves 0..13, one tile each) ----
        f32x4 accA = {0.f, 0.f, 0.f, 0.f};
        if (hasT) {
            #pragma unroll 4
            for (int rel = 0; rel < 16; ++rel) {
                uint4 bAu = wf[((l * 16 + rel) * 2 + NtA) * 64 + lane];
                const __half* up = Uh + (MtA * 16 + ln15) * UROW + rel * 32 + q8;
                f16x8 af = two_u2(*(const uint2*)up, *(const uint2*)(up + 4));
                accA = __builtin_amdgcn_mfma_f32_16x16x32_f16(af, u4_to_f16x8(bAu), accA, 0, 0, 0);
            }
        }
        // P8: h = relu(0.5*(agg+bias) + 0.5*h); zero eh/et/den for next layer
        if (l == 0)
            for (int i = t; i < 300; i += 1024) ((uint4*)(smem + S_EH))[i] = make_uint4(0, 0, 0, 0);
        if (hasT) {
            int dcol = NtA * 16 + ln15;
            float bias = h_bias[l * 32 + dcol];
            #pragma unroll
            for (int i = 0; i < 4; ++i) {
                int n = MtA * 16 + q * 4 + i;
                if (n < 100) {
                    float hold = __half2float(hH[n * 40 + dcol]);
                    float hn = fmaxf(0.f, 0.5f * (accA[i] + bias) + 0.5f * hold);
                    hH[n * 40 + dcol] = __float2half(hn);
                }
            }
        }
    }
    __syncthreads();   // h final

    // P9: readout x[g] = sum_n h[n] * rw[n]   (red buffer reuses U region)
    float* redp = (float*)(smem + S_U);
    {
        int part = t >> 5, d = t & 31;
        float acc = 0.f;
        for (int n = part; n < 100; n += 32)
            acc += __half2float(hH[n * 40 + d]) * rw[g * 100 + n];
        redp[part * 32 + d] = acc;
    }
    __syncthreads();
    if (t < 32) {
        float s = 0.f;
        #pragma unroll
        for (int p = 0; p < 32; ++p) s += redp[p * 32 + t];
        xout[g * 32 + t] = s;
    }
}

extern "C" void kernel_launch(void* const* d_in, const int* in_sizes, int n_in,
                              void* d_out, int out_size, void* d_ws, size_t ws_size,
                              hipStream_t stream) {
    const float* state     = (const float*)d_in[0];
    const float* rw        = (const float*)d_in[1];
    const float* code_emb  = (const float*)d_in[2];
    const float* rel_table = (const float*)d_in[3];
    const float* W         = (const float*)d_in[4];
    const float* h_bias    = (const float*)d_in[5];
    const float* Wr        = (const float*)d_in[6];
    const float* br        = (const float*)d_in[7];
    const float* We        = (const float*)d_in[8];
    const float* be        = (const float*)d_in[9];
    const float* attn_h    = (const float*)d_in[10];
    const float* attn_t    = (const float*)d_in[11];
    const float* attn_s    = (const float*)d_in[12];
    const float* attn_r    = (const float*)d_in[13];
    const float* attn_rs   = (const float*)d_in[14];
    const int* node_ids    = (const int*)d_in[15];
    const int* src         = (const int*)d_in[16];
    const int* dst         = (const int*)d_in[17];
    const int* rtype       = (const int*)d_in[18];

    float* out = (float*)d_out;
    float* xout = out;
    float* relOut = out + (size_t)NGRAPH * 32;
    float* edgeOut = relOut + (size_t)EDGES * 4;

    int* wsi = (int*)d_ws;
    float* wsf = (float*)d_ws;
    int* hist = wsi + WI_HIST;
    int* off  = wsi + WI_OFF;
    int* curs = wsi + WI_CURS;
    int* meta = wsi + WI_META;
    int* orig = wsi + WI_ORIG;
    float* prep = wsf + WF_PREP;
    uint4* wfrag = (uint4*)(wsf + WF_WFRAG);

    (void)hipMemsetAsync(hist, 0, NBIN * sizeof(int), stream);
    k_hist<<<(EDGES + 255) / 256, 256, 0, stream>>>(dst, rtype, hist);
    k_scan<<<1, 1024, 0, stream>>>(hist, off, curs);
    k_scatter<<<(EDGES + 255) / 256, 256, 0, stream>>>(src, dst, rtype, curs, meta, orig);
    k_setup<<<21, 256, 0, stream>>>(rel_table, Wr, br, We, be, attn_r, attn_rs, attn_s,
                                    W, prep, wfrag);

    (void)hipFuncSetAttribute((const void*)k_fused, hipFuncAttributeMaxDynamicSharedMemorySize, S_TOTAL);
    k_fused<<<NGRAPH, 1024, S_TOTAL, stream>>>(state, rw, code_emb, h_bias, be,
                                               attn_h, attn_t, node_ids, off, meta, orig,
                                               prep, wfrag, xout, relOut, edgeOut);
}

// Round 13
// 354.445 us; speedup vs baseline: 1.0183x; 1.0032x over previous
//
#include <hip/hip_runtime.h>
#include <hip/hip_fp16.h>

#define DI __device__ __forceinline__

constexpr int NGRAPH = 500;
constexpr int EDGES  = 800000;
constexpr int NBIN   = NGRAPH * 16;   // (graph, relation)

// ---- workspace layout (4-byte units) ----
constexpr size_t WI_HIST = 0;                    // [8000]
constexpr size_t WI_OFF  = WI_HIST + NBIN;       // [8001]
constexpr size_t WI_CURS = WI_OFF + NBIN + 1;    // [8000]
constexpr size_t WI_META = WI_CURS + NBIN;       // [E]
constexpr size_t WI_ORIG = WI_META + EDGES;      // [E]
constexpr size_t WF_PREP = WI_ORIG + EDGES;      // 656 floats
constexpr size_t WF_WFRAG = WF_PREP + 672;       // uint4[5120]: W-frags[4096] + We-frags[1024]

// ---- LDS layout (bytes), total 150064 -> 1 block/CU ----
constexpr int S_H    = 0;        // f16 h[100][40]   (cols 0..31 used)
constexpr int S_HP   = 8000;     // f16 hp[100][128] (col c -> d=c>>2, h=c&3), XOR-swizzled
constexpr int S_U    = 33600;    // f16 U[100][516]  (16 rels x 32 dims + pad)
constexpr int S_EH   = 136800;   // f32[100][4]
constexpr int S_ET   = 138400;   // f32[100][4]
constexpr int S_DEN  = 140000;   // f32[100][4]
constexpr int S_RA   = 141600;   // f32[16][4]
constexpr int S_ESG  = 141856;   // f32[4]
constexpr int S_META = 141872;   // i32[2048] staged edge meta
constexpr int S_TOTAL = S_META + 2048 * 4;   // 150064
constexpr int UROW = 516;        // f16 elems per U row

typedef _Float16 f16x8 __attribute__((ext_vector_type(8)));
typedef float f32x4 __attribute__((ext_vector_type(4)));

DI float lrelu(float x) { return x >= 0.f ? x : 0.2f * x; }
DI f16x8 u4_to_f16x8(uint4 u) { f16x8 r; __builtin_memcpy(&r, &u, 16); return r; }
DI f16x8 two_u2(uint2 a, uint2 b) { return u4_to_f16x8(make_uint4(a.x, a.y, b.x, b.y)); }

// hp swizzle: half-index for (node n, col c); XOR bits 3..5 with n&7 (16B granularity)
DI int hpIdx(int n, int c) { return n * 128 + (c ^ ((n & 7) << 3)); }

// packed f16 LDS atomic add (ds_pk_add_f16); __syncthreads() orders U reads after.
DI void ldsPkAddF16(__half* p, float v0, float v1) {
    __half2 hv = __floats2half2_rn(v0, v1);
    unsigned uv; __builtin_memcpy(&uv, &hv, 4);
    unsigned addr = (unsigned)(unsigned long long)p;
    asm volatile("ds_pk_add_f16 %0, %1" :: "v"(addr), "v"(uv));
}

// ---------------- binning: (graph, relation) bins, ~100 edges/bin ----------------
__global__ void k_hist(const int* __restrict__ dst, const int* __restrict__ rt,
                       int* __restrict__ hist) {
    int e = blockIdx.x * 256 + threadIdx.x;
    if (e >= EDGES) return;
    unsigned g = (unsigned)dst[e] / 100u;
    atomicAdd(&hist[g * 16 + rt[e]], 1);
}

__global__ void k_scan(const int* __restrict__ hist, int* __restrict__ off,
                       int* __restrict__ curs) {
    __shared__ int sc[1024];
    int t = threadIdx.x;
    int v[8]; int s = 0;
    #pragma unroll
    for (int i = 0; i < 8; ++i) { int b = t*8 + i; v[i] = (b < NBIN) ? hist[b] : 0; s += v[i]; }
    sc[t] = s; __syncthreads();
    for (int o = 1; o < 1024; o <<= 1) {
        int a = (t >= o) ? sc[t - o] : 0;
        __syncthreads();
        sc[t] += a;
        __syncthreads();
    }
    int run = sc[t] - s;
    #pragma unroll
    for (int i = 0; i < 8; ++i) {
        int b = t*8 + i;
        if (b < NBIN) { off[b] = run; curs[b] = run; }
        run += v[i];
    }
    if (t == 0) off[NBIN] = EDGES;
}

__global__ void k_scatter(const int* __restrict__ src, const int* __restrict__ dst,
                          const int* __restrict__ rt, int* __restrict__ curs,
                          int* __restrict__ meta, int* __restrict__ orig) {
    int e = blockIdx.x * 256 + threadIdx.x;
    if (e >= EDGES) return;
    int s = src[e], d = dst[e], r = rt[e];
    int g = (unsigned)d / 100u;
    int pos = atomicAdd(&curs[g * 16 + r], 1);
    meta[pos] = (s - g * 100) | ((d - g * 100) << 7) | (r << 14);
    orig[pos] = e;
}

// ---------------- setup: prep folds + f16 MFMA fragments ----------------
__global__ void k_setup(const float* __restrict__ rel_table, const float* __restrict__ Wr,
                        const float* __restrict__ br, const float* __restrict__ We,
                        const float* __restrict__ be, const float* __restrict__ attn_r,
                        const float* __restrict__ attn_rs, const float* __restrict__ attn_s,
                        const float* __restrict__ W, float* __restrict__ prep,
                        uint4* __restrict__ wf) {
    __shared__ float wra[2][32][4];
    __shared__ float sbias[2][3][4];
    int b = blockIdx.x, t = threadIdx.x;
    if (b == 0) {
        {
            int l = t >> 7, k = (t >> 2) & 31, h = t & 3;
            float a = 0.f, bb = 0.f, c = 0.f;
            for (int d2 = 0; d2 < 32; ++d2) {
                float w1 = Wr[(size_t)(l*32 + k)*128 + h*32 + d2];
                float w2 = We[(size_t)(l*32 + k)*128 + h*32 + d2];
                a  += w1 * attn_r [l*128 + h*32 + d2];
                bb += w1 * attn_rs[l*128 + h*32 + d2];
                c  += w2 * attn_s [l*128 + h*32 + d2];
            }
            wra[l][k][h] = a;
            prep[128 + (l*32 + k)*4 + h] = bb;
            prep[384 + (l*32 + k)*4 + h] = c;
        }
        if (t < 24) {
            int l = t / 12, which = (t % 12) / 4, h = t % 4;
            const float* bp = (which == 2) ? be : br;
            const float* ap = (which == 0) ? attn_r : (which == 1 ? attn_rs : attn_s);
            float s = 0.f;
            for (int d2 = 0; d2 < 32; ++d2) s += bp[l*128 + h*32 + d2] * ap[l*128 + h*32 + d2];
            sbias[l][which][h] = s;
        }
        __syncthreads();
        if (t < 128) {
            int l = t >> 6, r = (t >> 2) & 15, h = t & 3;
            float s = sbias[l][0][h];
            for (int k = 0; k < 32; ++k) s += rel_table[r*32 + k] * wra[l][k][h];
            prep[(l*16 + r)*4 + h] = s;
        }
        if (t < 8) {
            int l = t >> 2, h = t & 3;
            prep[640 + l*4 + h] = sbias[l][1][h];
            prep[648 + l*4 + h] = sbias[l][2][h];
        }
    } else if (b <= 16) {
        // W fragments (f16): wf[((l*16+rel)*2+Nt)*64 + ln]
        int fi = (b - 1) * 256 + t;
        int ln = fi & 63, Nt = (fi >> 6) & 1, rel = (fi >> 7) & 15, l = fi >> 11;
        int j = Nt*16 + (ln & 15), k0 = (ln >> 4) << 3;
        unsigned short fr[8];
        #pragma unroll
        for (int i = 0; i < 8; ++i) {
            __half hv = __float2half(W[(((size_t)l*16 + rel)*32 + k0 + i)*32 + j]);
            __builtin_memcpy(&fr[i], &hv, 2);
        }
        uint4 o;
        o.x = fr[0] | ((unsigned)fr[1] << 16);
        o.y = fr[2] | ((unsigned)fr[3] << 16);
        o.z = fr[4] | ((unsigned)fr[5] << 16);
        o.w = fr[6] | ((unsigned)fr[7] << 16);
        wf[fi] = o;
    } else {
        // We fragments (f16, column-permuted): col c -> phys (c&3)*32+(c>>2)
        int fi = (b - 17) * 256 + t;
        int ln = fi & 63, Nt = (fi >> 6) & 7, l = fi >> 9;
        int c = Nt*16 + (ln & 15);
        int phys = (c & 3)*32 + (c >> 2);
        int k0 = (ln >> 4) << 3;
        unsigned short fr[8];
        #pragma unroll
        for (int i = 0; i < 8; ++i) {
            __half hv = __float2half(We[(size_t)l*4096 + (k0 + i)*128 + phys]);
            __builtin_memcpy(&fr[i], &hv, 2);
        }
        uint4 o;
        o.x = fr[0] | ((unsigned)fr[1] << 16);
        o.y = fr[2] | ((unsigned)fr[3] << 16);
        o.z = fr[4] | ((unsigned)fr[5] << 16);
        o.w = fr[6] | ((unsigned)fr[7] << 16);
        wf[4096 + fi] = o;
    }
}

// ---------------- fused per-graph forward: 1024 threads, quad-split edges ----------------
__global__ void __launch_bounds__(1024, 1)
k_fused(const float* __restrict__ state, const float* __restrict__ rw,
        const float* __restrict__ code_emb, const float* __restrict__ h_bias,
        const float* __restrict__ be, const float* __restrict__ attn_h,
        const float* __restrict__ attn_t, const int* __restrict__ node_ids,
        const int* __restrict__ off, const int* __restrict__ meta,
        const int* __restrict__ orig, const float* __restrict__ prep,
        const uint4* __restrict__ wf,
        float* __restrict__ xout, float* __restrict__ relOut, float* __restrict__ edgeOut) {
    extern __shared__ char smem[];
    __half* hH  = (__half*)(smem + S_H);
    __half* hpH = (__half*)(smem + S_HP);
    __half* Uh  = (__half*)(smem + S_U);
    float* ehp  = (float*)(smem + S_EH);
    float* etp  = (float*)(smem + S_ET);
    float* denp = (float*)(smem + S_DEN);
    float* rap  = (float*)(smem + S_RA);
    float* esgp = (float*)(smem + S_ESG);
    int*   mlds = (int*)(smem + S_META);
    const uint4* wfe = wf + 4096;

    const int g = blockIdx.x;
    const int t = threadIdx.x;
    const int lane = t & 63, w = t >> 6;          // 16 waves
    const int ln15 = lane & 15, q = lane >> 4, q8 = q << 3;
    // P7/P8 tile (waves 0..13)
    const int MtA = w % 7, NtA = w / 7;
    const bool hasT = (w < 14);
    // X1 column-group: wave pair shares cg; even wave Mt 0..3, odd Mt 4..6
    const int cg = w >> 1;
    const int colc = cg * 16 + ln15;
    const int physc = (colc & 3) * 32 + (colc >> 2);
    const int Mt0 = (w & 1) ? 4 : 0;
    const int Mt1 = (w & 1) ? 7 : 4;

    const int gbase = off[g * 16];
    const int ecnt  = off[g * 16 + 16] - gbase;
    const int nq    = ecnt << 2;                  // edge-quarters

    // P0: h0 = code_emb[node_ids] (f16, [100][40]); zero eh/et/den; stage meta to LDS
    for (int i = t; i < 1600; i += 1024) {
        int n = i >> 4, dp = i & 15;
        int id = node_ids[g * 100 + n];
        float2 v = *(const float2*)&code_emb[(size_t)id * 32 + dp * 2];
        *(__half2*)&hH[n * 40 + dp * 2] = __floats2half2_rn(v.x, v.y);
    }
    for (int i = t; i < 300; i += 1024) ((uint4*)(smem + S_EH))[i] = make_uint4(0, 0, 0, 0);
    for (int i = t; i < 2048; i += 1024) mlds[i] = (i < ecnt) ? meta[gbase + i] : -1;

    // scatter ALL edge-quarters: thread = (edge, dim-quad j); 4 reads + 4 pk_adds each
    auto scatterAll = [&](bool writeAtt) {
        float4 esg4 = *(const float4*)esgp;
        for (int it = t; it < nq; it += 1024) {
            int e = it >> 2, j = it & 3;
            int m = mlds[e];
            int s = m & 127, d = (m >> 7) & 127, r = (m >> 14) & 15;
            int cb = r * 32;
            int sw = (s & 7) << 3;
            float4 eh4 = *(const float4*)&ehp[s * 4];
            float4 et4 = *(const float4*)&etp[d * 4];
            float4 dn  = *(const float4*)&denp[d * 4];
            float4 r4  = *(const float4*)&rap[r * 4];
            float a0 = __expf(lrelu(eh4.x + et4.x + esg4.x)) / dn.x;
            float a1 = __expf(lrelu(eh4.y + et4.y + esg4.y)) / dn.y;
            float a2 = __expf(lrelu(eh4.z + et4.z + esg4.z)) / dn.z;
            float a3 = __expf(lrelu(eh4.w + et4.w + esg4.w)) / dn.w;
            if (writeAtt && j == 0) {
                int oe = orig[gbase + e];
                *(float4*)&edgeOut[(size_t)oe * 4] = make_float4(a0, a1, a2, a3);
                *(float4*)&relOut[(size_t)oe * 4] = r4;
            }
            float c0 = a0 * r4.x, c1 = a1 * r4.y, c2 = a2 * r4.z, c3 = a3 * r4.w;
            #pragma unroll
            for (int i = 0; i < 4; ++i) {
                int db = j * 4 + i;
                uint4 hv = *(const uint4*)&hpH[s * 128 + ((db * 8) ^ sw)];
                float2 f01 = __half22float2(*(const __half2*)&hv.x);
                float2 f23 = __half22float2(*(const __half2*)&hv.y);
                float2 f45 = __half22float2(*(const __half2*)&hv.z);
                float2 f67 = __half22float2(*(const __half2*)&hv.w);
                float v0 = c0*f01.x + c1*f01.y + c2*f23.x + c3*f23.y;
                float v1 = c0*f45.x + c1*f45.y + c2*f67.x + c3*f67.y;
                ldsPkAddF16(Uh + d * UROW + cb + db * 2, v0, v1);
            }
        }
    };

    for (int l = 0; l < 2; ++l) {
        __syncthreads();   // B0: h ready, eh/et/den zeroed, U free

        // ---- X1: zero U; P2-MFMA (hp = h@We + be) + eh/et epilogue; P1 rel-att ----
        for (int i = t; i < 6450; i += 1024) ((uint4*)(smem + S_U))[i] = make_uint4(0, 0, 0, 0);
        {
            uint4 bwe = wfe[(l * 8 + cg) * 64 + lane];
            f16x8 bw = u4_to_f16x8(bwe);
            float beC = be[l * 128 + physc];
            float ahC = attn_h[l * 128 + physc];
            float atC = attn_t[l * 128 + physc];
            f32x4 z = {0.f, 0.f, 0.f, 0.f};
            for (int Mt = Mt0; Mt < Mt1; ++Mt) {
                const __half* hr = hH + (Mt * 16 + ln15) * 40 + q8;
                f32x4 pc = __builtin_amdgcn_mfma_f32_16x16x32_f16(
                    two_u2(*(const uint2*)hr, *(const uint2*)(hr + 4)), bw, z, 0, 0, 0);
                #pragma unroll
                for (int i = 0; i < 4; ++i) {
                    int n = Mt * 16 + q * 4 + i;
                    float hv = pc[i] + beC;
                    bool ok = (n < 100);
                    if (ok) hpH[hpIdx(n, colc)] = __float2half(hv);
                    float veh = ok ? hv * ahC : 0.f;
                    float vet = ok ? hv * atC : 0.f;
                    veh += __shfl_xor(veh, 4); vet += __shfl_xor(vet, 4);
                    veh += __shfl_xor(veh, 8); vet += __shfl_xor(vet, 8);
                    if (ok && (ln15 & 12) == 0) {
                        atomicAdd(&ehp[n * 4 + (ln15 & 3)], veh);
                        atomicAdd(&etp[n * 4 + (ln15 & 3)], vet);
                    }
                }
            }
        }
        {   // P1: relation attention (all waves redundantly; benign same-value races)
            int k32 = lane & 31;
            float sG = state[g * 32 + k32];
            float4 frs = *(const float4*)&prep[128 + l * 128 + k32 * 4];
            float4 fes = *(const float4*)&prep[384 + l * 128 + k32 * 4];
            float p0 = sG * frs.x, p1 = sG * frs.y, p2 = sG * frs.z, p3 = sG * frs.w;
            float q0 = sG * fes.x, q1 = sG * fes.y, q2 = sG * fes.z, q3 = sG * fes.w;
            #pragma unroll
            for (int m = 1; m < 32; m <<= 1) {
                p0 += __shfl_xor(p0, m); p1 += __shfl_xor(p1, m);
                p2 += __shfl_xor(p2, m); p3 += __shfl_xor(p3, m);
                q0 += __shfl_xor(q0, m); q1 += __shfl_xor(q1, m);
                q2 += __shfl_xor(q2, m); q3 += __shfl_xor(q3, m);
            }
            int h = lane & 3;
            float esh  = (h & 2) ? ((h & 1) ? p3 : p2) : ((h & 1) ? p1 : p0);
            float esgh = (h & 2) ? ((h & 1) ? q3 : q2) : ((h & 1) ? q1 : q0);
            esh  += prep[640 + l * 4 + h];
            esgh += prep[648 + l * 4 + h];
            if (lane < 4) esgp[lane] = esgh;
            float er = prep[l * 64 + lane];
            float ex = __expf(lrelu(er + esh));
            float s = ex;
            s += __shfl_xor(s, 4); s += __shfl_xor(s, 8);
            s += __shfl_xor(s, 16); s += __shfl_xor(s, 32);
            rap[lane] = ex / s;
        }
        __syncthreads();   // B1: hp/eh/et/rap/esg ready, U zeroed

        // ---- X2: edge exp -> den (quad-split: one head per lane) ----
        for (int it = t; it < nq; it += 1024) {
            int e = it >> 2, j = it & 3;
            int m = mlds[e];
            int s = m & 127, d = (m >> 7) & 127;
            float val = __expf(lrelu(ehp[s * 4 + j] + etp[d * 4 + j] + esgp[j]));
            atomicAdd(&denp[d * 4 + j], val);
        }
        __syncthreads();   // B2: den final

        scatterAll(l == 1);
        __syncthreads();   // B3: U complete

        // ---- P7: 16-relation MFMA chain (waves 0..13, one tile each) ----
        f32x4 accA = {0.f, 0.f, 0.f, 0.f};
        if (hasT) {
            #pragma unroll 4
            for (int rel = 0; rel < 16; ++rel) {
                uint4 bAu = wf[((l * 16 + rel) * 2 + NtA) * 64 + lane];
                const __half* up = Uh + (MtA * 16 + ln15) * UROW + rel * 32 + q8;
                f16x8 af = two_u2(*(const uint2*)up, *(const uint2*)(up + 4));
                accA = __builtin_amdgcn_mfma_f32_16x16x32_f16(af, u4_to_f16x8(bAu), accA, 0, 0, 0);
            }
        }
        // P8: h = relu(0.5*(agg+bias) + 0.5*h); zero eh/et/den for next layer
        if (l == 0)
            for (int i = t; i < 300; i += 1024) ((uint4*)(smem + S_EH))[i] = make_uint4(0, 0, 0, 0);
        if (hasT) {
            int dcol = NtA * 16 + ln15;
            float bias = h_bias[l * 32 + dcol];
            #pragma unroll
            for (int i = 0; i < 4; ++i) {
                int n = MtA * 16 + q * 4 + i;
                if (n < 100) {
                    float hold = __half2float(hH[n * 40 + dcol]);
                    float hn = fmaxf(0.f, 0.5f * (accA[i] + bias) + 0.5f * hold);
                    hH[n * 40 + dcol] = __float2half(hn);
                }
            }
        }
    }
    __syncthreads();   // h final

    // P9: readout x[g] = sum_n h[n] * rw[n]   (red buffer reuses U region)
    float* redp = (float*)(smem + S_U);
    {
        int part = t >> 5, d = t & 31;
        float acc = 0.f;
        for (int n = part; n < 100; n += 32)
            acc += __half2float(hH[n * 40 + d]) * rw[g * 100 + n];
        redp[part * 32 + d] = acc;
    }
    __syncthreads();
    if (t < 32) {
        float s = 0.f;
        #pragma unroll
        for (int p = 0; p < 32; ++p) s += redp[p * 32 + t];
        xout[g * 32 + t] = s;
    }
}

extern "C" void kernel_launch(void* const* d_in, const int* in_sizes, int n_in,
                              void* d_out, int out_size, void* d_ws, size_t ws_size,
                              hipStream_t stream) {
    const float* state     = (const float*)d_in[0];
    const float* rw        = (const float*)d_in[1];
    const float* code_emb  = (const float*)d_in[2];
    const float* rel_table = (const float*)d_in[3];
    const float* W         = (const float*)d_in[4];
    const float* h_bias    = (const float*)d_in[5];
    const float* Wr        = (const float*)d_in[6];
    const float* br        = (const float*)d_in[7];
    const float* We        = (const float*)d_in[8];
    const float* be        = (const float*)d_in[9];
    const float* attn_h    = (const float*)d_in[10];
    const float* attn_t    = (const float*)d_in[11];
    const float* attn_s    = (const float*)d_in[12];
    const float* attn_r    = (const float*)d_in[13];
    const float* attn_rs   = (const float*)d_in[14];
    const int* node_ids    = (const int*)d_in[15];
    const int* src         = (const int*)d_in[16];
    const int* dst         = (const int*)d_in[17];
    const int* rtype       = (const int*)d_in[18];

    float* out = (float*)d_out;
    float* xout = out;
    float* relOut = out + (size_t)NGRAPH * 32;
    float* edgeOut = relOut + (size_t)EDGES * 4;

    int* wsi = (int*)d_ws;
    float* wsf = (float*)d_ws;
    int* hist = wsi + WI_HIST;
    int* off  = wsi + WI_OFF;
    int* curs = wsi + WI_CURS;
    int* meta = wsi + WI_META;
    int* orig = wsi + WI_ORIG;
    float* prep = wsf + WF_PREP;
    uint4* wfrag = (uint4*)(wsf + WF_WFRAG);

    (void)hipMemsetAsync(hist, 0, NBIN * sizeof(int), stream);
    k_hist<<<(EDGES + 255) / 256, 256, 0, stream>>>(dst, rtype, hist);
    k_scan<<<1, 1024, 0, stream>>>(hist, off, curs);
    k_scatter<<<(EDGES + 255) / 256, 256, 0, stream>>>(src, dst, rtype, curs, meta, orig);
    k_setup<<<21, 256, 0, stream>>>(rel_table, Wr, br, We, be, attn_r, attn_rs, attn_s,
                                    W, prep, wfrag);

    (void)hipFuncSetAttribute((const void*)k_fused, hipFuncAttributeMaxDynamicSharedMemorySize, S_TOTAL);
    k_fused<<<NGRAPH, 1024, S_TOTAL, stream>>>(state, rw, code_emb, h_bias, be,
                                               attn_h, attn_t, node_ids, off, meta, orig,
                                               prep, wfrag, xout, relOut, edgeOut);
}

// Round 14
// 331.126 us; speedup vs baseline: 1.0900x; 1.0704x over previous
//
#include <hip/hip_runtime.h>
#include <hip/hip_fp16.h>

#define DI __device__ __forceinline__

constexpr int NGRAPH = 500;
constexpr int EDGES  = 800000;
constexpr int NBIN   = NGRAPH * 16;   // (graph, relation)
constexpr int CAP    = 192;           // slots per bin (mean fill 100, sd ~10)

// ---- workspace layout (4-byte units) ----
constexpr size_t WI_CURS  = 0;                          // [8000] counters -> counts
constexpr size_t WI_SMETA = 8192;                       // [NBIN*CAP]
constexpr size_t WI_SORIG = WI_SMETA + (size_t)NBIN * CAP;
constexpr size_t WF_PREP  = WI_SORIG + (size_t)NBIN * CAP;   // 656 floats
constexpr size_t WF_WFRAG = WF_PREP + 672;              // uint4[5120]

// ---- LDS layout (bytes), total 158256 -> 1 block/CU ----
constexpr int S_H    = 0;        // f16 h[100][40]   (cols 0..31 used)
constexpr int S_HP   = 8000;     // f16 hp[100][128] (col c -> d=c>>2, h=c&3), XOR-swizzled
constexpr int S_U    = 33600;    // f16 U[100][516]  (16 rels x 32 dims + pad)
constexpr int S_EH   = 136800;   // f32[100][4]
constexpr int S_ET   = 138400;   // f32[100][4]
constexpr int S_DEN  = 140000;   // f32[100][4]
constexpr int S_RA   = 141600;   // f32[16][4] (doubles as cnt[16] scratch pre-B0)
constexpr int S_ESG  = 141856;   // f32[4]
constexpr int S_META = 141872;   // i32[2048] staged edge meta
constexpr int S_OG   = 150064;   // i32[2048] staged orig ids
constexpr int S_TOTAL = S_OG + 2048 * 4;   // 158256
constexpr int UROW = 516;        // f16 elems per U row

typedef _Float16 f16x8 __attribute__((ext_vector_type(8)));
typedef float f32x4 __attribute__((ext_vector_type(4)));

DI float lrelu(float x) { return x >= 0.f ? x : 0.2f * x; }
DI f16x8 u4_to_f16x8(uint4 u) { f16x8 r; __builtin_memcpy(&r, &u, 16); return r; }
DI f16x8 two_u2(uint2 a, uint2 b) { return u4_to_f16x8(make_uint4(a.x, a.y, b.x, b.y)); }

// hp swizzle: half-index for (node n, col c); XOR bits 3..5 with n&7 (16B granularity)
DI int hpIdx(int n, int c) { return n * 128 + (c ^ ((n & 7) << 3)); }

// packed f16 LDS atomic add (ds_pk_add_f16); __syncthreads() orders U reads after.
DI void ldsPkAddF16(__half* p, float v0, float v1) {
    __half2 hv = __floats2half2_rn(v0, v1);
    unsigned uv; __builtin_memcpy(&uv, &hv, 4);
    unsigned addr = (unsigned)(unsigned long long)p;
    asm volatile("ds_pk_add_f16 %0, %1" :: "v"(addr), "v"(uv));
}

// ---------------- slot scatter: no hist, no scan ----------------
__global__ void k_scatter(const int* __restrict__ src, const int* __restrict__ dst,
                          const int* __restrict__ rt, int* __restrict__ curs,
                          int* __restrict__ smeta, int* __restrict__ sorig) {
    int e = blockIdx.x * 256 + threadIdx.x;
    if (e >= EDGES) return;
    int s = src[e], d = dst[e], r = rt[e];
    int g = (unsigned)d / 100u;
    int bin = g * 16 + r;
    int pos = atomicAdd(&curs[bin], 1);
    if (pos < CAP) {
        smeta[(size_t)bin * CAP + pos] = (s - g * 100) | ((d - g * 100) << 7) | (r << 14);
        sorig[(size_t)bin * CAP + pos] = e;
    }
}

// ---------------- setup: prep folds + f16 MFMA fragments ----------------
__global__ void k_setup(const float* __restrict__ rel_table, const float* __restrict__ Wr,
                        const float* __restrict__ br, const float* __restrict__ We,
                        const float* __restrict__ be, const float* __restrict__ attn_r,
                        const float* __restrict__ attn_rs, const float* __restrict__ attn_s,
                        const float* __restrict__ W, float* __restrict__ prep,
                        uint4* __restrict__ wf) {
    __shared__ float wra[2][32][4];
    __shared__ float sbias[2][3][4];
    int b = blockIdx.x, t = threadIdx.x;
    if (b == 0) {
        {
            int l = t >> 7, k = (t >> 2) & 31, h = t & 3;
            float a = 0.f, bb = 0.f, c = 0.f;
            for (int d2 = 0; d2 < 32; ++d2) {
                float w1 = Wr[(size_t)(l*32 + k)*128 + h*32 + d2];
                float w2 = We[(size_t)(l*32 + k)*128 + h*32 + d2];
                a  += w1 * attn_r [l*128 + h*32 + d2];
                bb += w1 * attn_rs[l*128 + h*32 + d2];
                c  += w2 * attn_s [l*128 + h*32 + d2];
            }
            wra[l][k][h] = a;
            prep[128 + (l*32 + k)*4 + h] = bb;
            prep[384 + (l*32 + k)*4 + h] = c;
        }
        if (t < 24) {
            int l = t / 12, which = (t % 12) / 4, h = t % 4;
            const float* bp = (which == 2) ? be : br;
            const float* ap = (which == 0) ? attn_r : (which == 1 ? attn_rs : attn_s);
            float s = 0.f;
            for (int d2 = 0; d2 < 32; ++d2) s += bp[l*128 + h*32 + d2] * ap[l*128 + h*32 + d2];
            sbias[l][which][h] = s;
        }
        __syncthreads();
        if (t < 128) {
            int l = t >> 6, r = (t >> 2) & 15, h = t & 3;
            float s = sbias[l][0][h];
            for (int k = 0; k < 32; ++k) s += rel_table[r*32 + k] * wra[l][k][h];
            prep[(l*16 + r)*4 + h] = s;
        }
        if (t < 8) {
            int l = t >> 2, h = t & 3;
            prep[640 + l*4 + h] = sbias[l][1][h];
            prep[648 + l*4 + h] = sbias[l][2][h];
        }
    } else if (b <= 16) {
        // W fragments (f16): wf[((l*16+rel)*2+Nt)*64 + ln]
        int fi = (b - 1) * 256 + t;
        int ln = fi & 63, Nt = (fi >> 6) & 1, rel = (fi >> 7) & 15, l = fi >> 11;
        int j = Nt*16 + (ln & 15), k0 = (ln >> 4) << 3;
        unsigned short fr[8];
        #pragma unroll
        for (int i = 0; i < 8; ++i) {
            __half hv = __float2half(W[(((size_t)l*16 + rel)*32 + k0 + i)*32 + j]);
            __builtin_memcpy(&fr[i], &hv, 2);
        }
        uint4 o;
        o.x = fr[0] | ((unsigned)fr[1] << 16);
        o.y = fr[2] | ((unsigned)fr[3] << 16);
        o.z = fr[4] | ((unsigned)fr[5] << 16);
        o.w = fr[6] | ((unsigned)fr[7] << 16);
        wf[fi] = o;
    } else {
        // We fragments (f16, column-permuted): col c -> phys (c&3)*32+(c>>2)
        int fi = (b - 17) * 256 + t;
        int ln = fi & 63, Nt = (fi >> 6) & 7, l = fi >> 9;
        int c = Nt*16 + (ln & 15);
        int phys = (c & 3)*32 + (c >> 2);
        int k0 = (ln >> 4) << 3;
        unsigned short fr[8];
        #pragma unroll
        for (int i = 0; i < 8; ++i) {
            __half hv = __float2half(We[(size_t)l*4096 + (k0 + i)*128 + phys]);
            __builtin_memcpy(&fr[i], &hv, 2);
        }
        uint4 o;
        o.x = fr[0] | ((unsigned)fr[1] << 16);
        o.y = fr[2] | ((unsigned)fr[3] << 16);
        o.z = fr[4] | ((unsigned)fr[5] << 16);
        o.w = fr[6] | ((unsigned)fr[7] << 16);
        wf[4096 + fi] = o;
    }
}

// ---------------- fused per-graph forward: 1024 threads, 16 waves ----------------
__global__ void __launch_bounds__(1024, 1)
k_fused(const float* __restrict__ state, const float* __restrict__ rw,
        const float* __restrict__ code_emb, const float* __restrict__ h_bias,
        const float* __restrict__ be, const float* __restrict__ attn_h,
        const float* __restrict__ attn_t, const int* __restrict__ node_ids,
        const int* __restrict__ cnt, const int* __restrict__ smeta,
        const int* __restrict__ sorig, const float* __restrict__ prep,
        const uint4* __restrict__ wf,
        float* __restrict__ xout, float* __restrict__ relOut, float* __restrict__ edgeOut) {
    extern __shared__ char smem[];
    __half* hH  = (__half*)(smem + S_H);
    __half* hpH = (__half*)(smem + S_HP);
    __half* Uh  = (__half*)(smem + S_U);
    float* ehp  = (float*)(smem + S_EH);
    float* etp  = (float*)(smem + S_ET);
    float* denp = (float*)(smem + S_DEN);
    float* rap  = (float*)(smem + S_RA);
    float* esgp = (float*)(smem + S_ESG);
    int*   mlds = (int*)(smem + S_META);
    int*   og   = (int*)(smem + S_OG);
    const uint4* wfe = wf + 4096;

    const int g = blockIdx.x;
    const int t = threadIdx.x;
    const int lane = t & 63, w = t >> 6;          // 16 waves
    const int ln15 = lane & 15, q = lane >> 4, q8 = q << 3;
    // P7/P8 tile (waves 0..13)
    const int MtA = w % 7, NtA = w / 7;
    const bool hasT = (w < 14);
    // X1 column-group: wave pair shares cg; even wave Mt 0..3, odd Mt 4..6
    const int cg = w >> 1;
    const int colc = cg * 16 + ln15;
    const int physc = (colc & 3) * 32 + (colc >> 2);
    const int Mt0 = (w & 1) ? 4 : 0;
    const int Mt1 = (w & 1) ? 7 : 4;

    // P0: h0 = code_emb[node_ids] (f16, [100][40]); zero eh/et/den; bin counts
    for (int i = t; i < 1600; i += 1024) {
        int n = i >> 4, dp = i & 15;
        int id = node_ids[g * 100 + n];
        float2 v = *(const float2*)&code_emb[(size_t)id * 32 + dp * 2];
        *(__half2*)&hH[n * 40 + dp * 2] = __floats2half2_rn(v.x, v.y);
    }
    for (int i = t; i < 300; i += 1024) ((uint4*)(smem + S_EH))[i] = make_uint4(0, 0, 0, 0);
    int* cntp = (int*)(smem + S_RA);              // rap region free until X1
    if (t < 16) cntp[t] = cnt[g * 16 + t];
    __syncthreads();   // counts visible

    // stage this graph's edges contiguously into LDS (16 bins walk)
    int ec = 0;
    #pragma unroll
    for (int b = 0; b < 16; ++b) {
        int c = cntp[b];
        const int* mp = smeta + (size_t)(g * 16 + b) * CAP;
        const int* op = sorig + (size_t)(g * 16 + b) * CAP;
        for (int i = t; i < c; i += 1024) { mlds[ec + i] = mp[i]; og[ec + i] = op[i]; }
        ec += c;
    }
    __syncthreads();   // stage complete

    // edge meta -> registers (2 slots per thread; 2048 >= max edges/graph)
    int em[2], or2[2];
    #pragma unroll
    for (int k = 0; k < 2; ++k) {
        int e = t + k * 1024;
        em[k]  = (e < ec) ? mlds[e] : -1;
        or2[k] = (e < ec) ? og[e] : 0;
    }

    // scatter ALL edges: coefficient from LDS state, 16 packed adds into U
    auto scatterAll = [&](bool writeAtt) {
        float4 esg4 = *(const float4*)esgp;
        #pragma unroll
        for (int k = 0; k < 2; ++k) {
            int m = em[k];
            if (m >= 0) {
                int s = m & 127, d = (m >> 7) & 127, r = (m >> 14) & 15;
                int cb = r * 32;
                int sw = (s & 7) << 3;
                float4 eh4 = *(const float4*)&ehp[s * 4];
                float4 et4 = *(const float4*)&etp[d * 4];
                float4 dn  = *(const float4*)&denp[d * 4];
                float4 r4  = *(const float4*)&rap[r * 4];
                float a0 = __expf(lrelu(eh4.x + et4.x + esg4.x)) / dn.x;
                float a1 = __expf(lrelu(eh4.y + et4.y + esg4.y)) / dn.y;
                float a2 = __expf(lrelu(eh4.z + et4.z + esg4.z)) / dn.z;
                float a3 = __expf(lrelu(eh4.w + et4.w + esg4.w)) / dn.w;
                if (writeAtt) {
                    int oe = or2[k];
                    *(float4*)&edgeOut[(size_t)oe * 4] = make_float4(a0, a1, a2, a3);
                    *(float4*)&relOut[(size_t)oe * 4] = r4;
                }
                float c0 = a0 * r4.x, c1 = a1 * r4.y, c2 = a2 * r4.z, c3 = a3 * r4.w;
                #pragma unroll 8
                for (int db = 0; db < 16; ++db) {
                    uint4 hv = *(const uint4*)&hpH[s * 128 + ((db * 8) ^ sw)];
                    float2 f01 = __half22float2(*(const __half2*)&hv.x);
                    float2 f23 = __half22float2(*(const __half2*)&hv.y);
                    float2 f45 = __half22float2(*(const __half2*)&hv.z);
                    float2 f67 = __half22float2(*(const __half2*)&hv.w);
                    float v0 = c0*f01.x + c1*f01.y + c2*f23.x + c3*f23.y;
                    float v1 = c0*f45.x + c1*f45.y + c2*f67.x + c3*f67.y;
                    ldsPkAddF16(Uh + d * UROW + cb + db * 2, v0, v1);
                }
            }
        }
    };

    for (int l = 0; l < 2; ++l) {
        __syncthreads();   // B0: h ready, eh/et/den zeroed, U free

        // ---- X1: zero U; P2-MFMA (hp = h@We + be) + eh/et epilogue; P1 rel-att ----
        for (int i = t; i < 6450; i += 1024) ((uint4*)(smem + S_U))[i] = make_uint4(0, 0, 0, 0);
        {
            uint4 bwe = wfe[(l * 8 + cg) * 64 + lane];
            f16x8 bw = u4_to_f16x8(bwe);
            float beC = be[l * 128 + physc];
            float ahC = attn_h[l * 128 + physc];
            float atC = attn_t[l * 128 + physc];
            f32x4 z = {0.f, 0.f, 0.f, 0.f};
            for (int Mt = Mt0; Mt < Mt1; ++Mt) {
                const __half* hr = hH + (Mt * 16 + ln15) * 40 + q8;
                f32x4 pc = __builtin_amdgcn_mfma_f32_16x16x32_f16(
                    two_u2(*(const uint2*)hr, *(const uint2*)(hr + 4)), bw, z, 0, 0, 0);
                #pragma unroll
                for (int i = 0; i < 4; ++i) {
                    int n = Mt * 16 + q * 4 + i;
                    float hv = pc[i] + beC;
                    bool ok = (n < 100);
                    if (ok) hpH[hpIdx(n, colc)] = __float2half(hv);
                    float veh = ok ? hv * ahC : 0.f;
                    float vet = ok ? hv * atC : 0.f;
                    veh += __shfl_xor(veh, 4); vet += __shfl_xor(vet, 4);
                    veh += __shfl_xor(veh, 8); vet += __shfl_xor(vet, 8);
                    if (ok && (ln15 & 12) == 0) {
                        atomicAdd(&ehp[n * 4 + (ln15 & 3)], veh);
                        atomicAdd(&etp[n * 4 + (ln15 & 3)], vet);
                    }
                }
            }
        }
        {   // P1: relation attention (all waves redundantly; benign same-value races)
            int k32 = lane & 31;
            float sG = state[g * 32 + k32];
            float4 frs = *(const float4*)&prep[128 + l * 128 + k32 * 4];
            float4 fes = *(const float4*)&prep[384 + l * 128 + k32 * 4];
            float p0 = sG * frs.x, p1 = sG * frs.y, p2 = sG * frs.z, p3 = sG * frs.w;
            float q0 = sG * fes.x, q1 = sG * fes.y, q2 = sG * fes.z, q3 = sG * fes.w;
            #pragma unroll
            for (int m = 1; m < 32; m <<= 1) {
                p0 += __shfl_xor(p0, m); p1 += __shfl_xor(p1, m);
                p2 += __shfl_xor(p2, m); p3 += __shfl_xor(p3, m);
                q0 += __shfl_xor(q0, m); q1 += __shfl_xor(q1, m);
                q2 += __shfl_xor(q2, m); q3 += __shfl_xor(q3, m);
            }
            int h = lane & 3;
            float esh  = (h & 2) ? ((h & 1) ? p3 : p2) : ((h & 1) ? p1 : p0);
            float esgh = (h & 2) ? ((h & 1) ? q3 : q2) : ((h & 1) ? q1 : q0);
            esh  += prep[640 + l * 4 + h];
            esgh += prep[648 + l * 4 + h];
            if (lane < 4) esgp[lane] = esgh;
            float er = prep[l * 64 + lane];
            float ex = __expf(lrelu(er + esh));
            float s = ex;
            s += __shfl_xor(s, 4); s += __shfl_xor(s, 8);
            s += __shfl_xor(s, 16); s += __shfl_xor(s, 32);
            rap[lane] = ex / s;
        }
        __syncthreads();   // B1: hp/eh/et/rap/esg ready, U zeroed

        // ---- X2: edge exp -> den ----
        {
            float4 esg4 = *(const float4*)esgp;
            #pragma unroll
            for (int k = 0; k < 2; ++k) {
                int m = em[k];
                if (m >= 0) {
                    int s = m & 127, d = (m >> 7) & 127;
                    float4 eh4 = *(const float4*)&ehp[s * 4];
                    float4 et4 = *(const float4*)&etp[d * 4];
                    atomicAdd(&denp[d * 4 + 0], __expf(lrelu(eh4.x + et4.x + esg4.x)));
                    atomicAdd(&denp[d * 4 + 1], __expf(lrelu(eh4.y + et4.y + esg4.y)));
                    atomicAdd(&denp[d * 4 + 2], __expf(lrelu(eh4.z + et4.z + esg4.z)));
                    atomicAdd(&denp[d * 4 + 3], __expf(lrelu(eh4.w + et4.w + esg4.w)));
                }
            }
        }
        __syncthreads();   // B2: den final

        scatterAll(l == 1);
        __syncthreads();   // B3: U complete

        // ---- P7: 16-relation MFMA chain (waves 0..13, one tile each) ----
        f32x4 accA = {0.f, 0.f, 0.f, 0.f};
        if (hasT) {
            #pragma unroll 4
            for (int rel = 0; rel < 16; ++rel) {
                uint4 bAu = wf[((l * 16 + rel) * 2 + NtA) * 64 + lane];
                const __half* up = Uh + (MtA * 16 + ln15) * UROW + rel * 32 + q8;
                f16x8 af = two_u2(*(const uint2*)up, *(const uint2*)(up + 4));
                accA = __builtin_amdgcn_mfma_f32_16x16x32_f16(af, u4_to_f16x8(bAu), accA, 0, 0, 0);
            }
        }
        // P8: h = relu(0.5*(agg+bias) + 0.5*h); zero eh/et/den for next layer
        if (l == 0)
            for (int i = t; i < 300; i += 1024) ((uint4*)(smem + S_EH))[i] = make_uint4(0, 0, 0, 0);
        if (hasT) {
            int dcol = NtA * 16 + ln15;
            float bias = h_bias[l * 32 + dcol];
            #pragma unroll
            for (int i = 0; i < 4; ++i) {
                int n = MtA * 16 + q * 4 + i;
                if (n < 100) {
                    float hold = __half2float(hH[n * 40 + dcol]);
                    float hn = fmaxf(0.f, 0.5f * (accA[i] + bias) + 0.5f * hold);
                    hH[n * 40 + dcol] = __float2half(hn);
                }
            }
        }
    }
    __syncthreads();   // h final

    // P9: readout x[g] = sum_n h[n] * rw[n]   (red buffer reuses U region)
    float* redp = (float*)(smem + S_U);
    {
        int part = t >> 5, d = t & 31;
        float acc = 0.f;
        for (int n = part; n < 100; n += 32)
            acc += __half2float(hH[n * 40 + d]) * rw[g * 100 + n];
        redp[part * 32 + d] = acc;
    }
    __syncthreads();
    if (t < 32) {
        float s = 0.f;
        #pragma unroll
        for (int p = 0; p < 32; ++p) s += redp[p * 32 + t];
        xout[g * 32 + t] = s;
    }
}

extern "C" void kernel_launch(void* const* d_in, const int* in_sizes, int n_in,
                              void* d_out, int out_size, void* d_ws, size_t ws_size,
                              hipStream_t stream) {
    const float* state     = (const float*)d_in[0];
    const float* rw        = (const float*)d_in[1];
    const float* code_emb  = (const float*)d_in[2];
    const float* rel_table = (const float*)d_in[3];
    const float* W         = (const float*)d_in[4];
    const float* h_bias    = (const float*)d_in[5];
    const float* Wr        = (const float*)d_in[6];
    const float* br        = (const float*)d_in[7];
    const float* We        = (const float*)d_in[8];
    const float* be        = (const float*)d_in[9];
    const float* attn_h    = (const float*)d_in[10];
    const float* attn_t    = (const float*)d_in[11];
    const float* attn_s    = (const float*)d_in[12];
    const float* attn_r    = (const float*)d_in[13];
    const float* attn_rs   = (const float*)d_in[14];
    const int* node_ids    = (const int*)d_in[15];
    const int* src         = (const int*)d_in[16];
    const int* dst         = (const int*)d_in[17];
    const int* rtype       = (const int*)d_in[18];

    float* out = (float*)d_out;
    float* xout = out;
    float* relOut = out + (size_t)NGRAPH * 32;
    float* edgeOut = relOut + (size_t)EDGES * 4;

    int* wsi = (int*)d_ws;
    float* wsf = (float*)d_ws;
    int* curs   = wsi + WI_CURS;
    int* smeta  = wsi + WI_SMETA;
    int* sorig  = wsi + WI_SORIG;
    float* prep = wsf + WF_PREP;
    uint4* wfrag = (uint4*)(wsf + WF_WFRAG);

    (void)hipMemsetAsync(curs, 0, NBIN * sizeof(int), stream);
    k_scatter<<<(EDGES + 255) / 256, 256, 0, stream>>>(src, dst, rtype, curs, smeta, sorig);
    k_setup<<<21, 256, 0, stream>>>(rel_table, Wr, br, We, be, attn_r, attn_rs, attn_s,
                                    W, prep, wfrag);

    (void)hipFuncSetAttribute((const void*)k_fused, hipFuncAttributeMaxDynamicSharedMemorySize, S_TOTAL);
    k_fused<<<NGRAPH, 1024, S_TOTAL, stream>>>(state, rw, code_emb, h_bias, be,
                                               attn_h, attn_t, node_ids, curs, smeta, sorig,
                                               prep, wfrag, xout, relOut, edgeOut);
}

// Round 15
// 195.783 us; speedup vs baseline: 1.8435x; 1.6913x over previous
//
#include <hip/hip_runtime.h>
#include <hip/hip_fp16.h>

#define DI __device__ __forceinline__

constexpr int NGRAPH = 500;
constexpr int EDGES  = 800000;
constexpr int NNODE  = 50000;
constexpr int CAP    = 56;            // slots per dst bin (Poisson mean 16, 10 sigma)

// ---- workspace layout (4-byte units) ----
constexpr size_t WI_CURS  = 0;                          // [50000]
constexpr size_t WI_SMETA = 50048;                      // [50000*56]
constexpr size_t WF_PREP  = WI_SMETA + (size_t)NNODE * CAP;  // 656 floats (pad 672)
constexpr size_t WF_WFRAG = WF_PREP + 672;              // uint4[5120]

// ---- LDS layout (bytes), total 151496 -> 1 block/CU ----
constexpr int S_H    = 0;        // f16 h[100][40] (cols 0..31 used)
constexpr int S_HP   = 8000;     // f16 hp[100][128] (col c -> d=c>>2,h=c&3), XOR-swizzled
constexpr int S_U    = 33600;    // f16 U[100][516]
constexpr int S_EH   = 136800;   // f32[100][4]
constexpr int S_ET   = 138400;   // f32[100][4]
constexpr int S_DEN  = 140000;   // f32[100][4]
constexpr int S_RA   = 141600;   // f32[16][4]
constexpr int S_ESG  = 141856;   // f32[4]
constexpr int S_AH   = 141872;   // f32[128] attn_h in hp-col order
constexpr int S_AT   = 142384;   // f32[128]
constexpr int S_MLDS = 142896;   // i32[2048] dst-sorted edge meta
constexpr int S_RP   = 151088;   // i32[102] rowptr
constexpr int S_TOTAL = 151496;
constexpr int UROW = 516;

typedef _Float16 f16x8 __attribute__((ext_vector_type(8)));
typedef float f32x4 __attribute__((ext_vector_type(4)));

DI float lrelu(float x) { return x >= 0.f ? x : 0.2f * x; }
DI f16x8 u4_to_f16x8(uint4 u) { f16x8 r; __builtin_memcpy(&r, &u, 16); return r; }
DI f16x8 two_u2(uint2 a, uint2 b) { return u4_to_f16x8(make_uint4(a.x, a.y, b.x, b.y)); }
DI float h2f(unsigned short u) { __half hv; __builtin_memcpy(&hv, &u, 2); return __half2float(hv); }

// hp swizzle: half-index for (node n, col c); XOR bits 3..5 with n&7 (16B granularity)
DI int hpIdx(int n, int c) { return n * 128 + (c ^ ((n & 7) << 3)); }

// ---------------- slot scatter by dst node ----------------
__global__ void k_scatter(const int* __restrict__ src, const int* __restrict__ dst,
                          const int* __restrict__ rt, int* __restrict__ curs,
                          int* __restrict__ smeta) {
    int e = blockIdx.x * 256 + threadIdx.x;
    if (e >= EDGES) return;
    int s = src[e], d = dst[e], r = rt[e];
    int g = (unsigned)d / 100u;
    int pos = atomicAdd(&curs[d], 1);
    if (pos < CAP)
        smeta[(size_t)d * CAP + pos] = (s - g * 100) | (r << 7) | (e << 11);
}

// ---------------- setup: prep folds + f16 MFMA fragments ----------------
__global__ void k_setup(const float* __restrict__ rel_table, const float* __restrict__ Wr,
                        const float* __restrict__ br, const float* __restrict__ We,
                        const float* __restrict__ be, const float* __restrict__ attn_r,
                        const float* __restrict__ attn_rs, const float* __restrict__ attn_s,
                        const float* __restrict__ W, float* __restrict__ prep,
                        uint4* __restrict__ wf) {
    __shared__ float wra[2][32][4];
    __shared__ float sbias[2][3][4];
    int b = blockIdx.x, t = threadIdx.x;
    if (b == 0) {
        {
            int l = t >> 7, k = (t >> 2) & 31, h = t & 3;
            float a = 0.f, bb = 0.f, c = 0.f;
            for (int d2 = 0; d2 < 32; ++d2) {
                float w1 = Wr[(size_t)(l*32 + k)*128 + h*32 + d2];
                float w2 = We[(size_t)(l*32 + k)*128 + h*32 + d2];
                a  += w1 * attn_r [l*128 + h*32 + d2];
                bb += w1 * attn_rs[l*128 + h*32 + d2];
                c  += w2 * attn_s [l*128 + h*32 + d2];
            }
            wra[l][k][h] = a;
            prep[128 + (l*32 + k)*4 + h] = bb;
            prep[384 + (l*32 + k)*4 + h] = c;
        }
        if (t < 24) {
            int l = t / 12, which = (t % 12) / 4, h = t % 4;
            const float* bp = (which == 2) ? be : br;
            const float* ap = (which == 0) ? attn_r : (which == 1 ? attn_rs : attn_s);
            float s = 0.f;
            for (int d2 = 0; d2 < 32; ++d2) s += bp[l*128 + h*32 + d2] * ap[l*128 + h*32 + d2];
            sbias[l][which][h] = s;
        }
        __syncthreads();
        if (t < 128) {
            int l = t >> 6, r = (t >> 2) & 15, h = t & 3;
            float s = sbias[l][0][h];
            for (int k = 0; k < 32; ++k) s += rel_table[r*32 + k] * wra[l][k][h];
            prep[(l*16 + r)*4 + h] = s;
        }
        if (t < 8) {
            int l = t >> 2, h = t & 3;
            prep[640 + l*4 + h] = sbias[l][1][h];
            prep[648 + l*4 + h] = sbias[l][2][h];
        }
    } else if (b <= 16) {
        // W fragments (f16): wf[((l*16+rel)*2+Nt)*64 + ln]
        int fi = (b - 1) * 256 + t;
        int ln = fi & 63, Nt = (fi >> 6) & 1, rel = (fi >> 7) & 15, l = fi >> 11;
        int j = Nt*16 + (ln & 15), k0 = (ln >> 4) << 3;
        unsigned short fr[8];
        #pragma unroll
        for (int i = 0; i < 8; ++i) {
            __half hv = __float2half(W[(((size_t)l*16 + rel)*32 + k0 + i)*32 + j]);
            __builtin_memcpy(&fr[i], &hv, 2);
        }
        uint4 o;
        o.x = fr[0] | ((unsigned)fr[1] << 16);
        o.y = fr[2] | ((unsigned)fr[3] << 16);
        o.z = fr[4] | ((unsigned)fr[5] << 16);
        o.w = fr[6] | ((unsigned)fr[7] << 16);
        wf[fi] = o;
    } else {
        // We fragments (f16, column-permuted): col c -> phys (c&3)*32+(c>>2)
        int fi = (b - 17) * 256 + t;
        int ln = fi & 63, Nt = (fi >> 6) & 7, l = fi >> 9;
        int c = Nt*16 + (ln & 15);
        int phys = (c & 3)*32 + (c >> 2);
        int k0 = (ln >> 4) << 3;
        unsigned short fr[8];
        #pragma unroll
        for (int i = 0; i < 8; ++i) {
            __half hv = __float2half(We[(size_t)l*4096 + (k0 + i)*128 + phys]);
            __builtin_memcpy(&fr[i], &hv, 2);
        }
        uint4 o;
        o.x = fr[0] | ((unsigned)fr[1] << 16);
        o.y = fr[2] | ((unsigned)fr[3] << 16);
        o.z = fr[4] | ((unsigned)fr[5] << 16);
        o.w = fr[6] | ((unsigned)fr[7] << 16);
        wf[4096 + fi] = o;
    }
}

// ---------------- fused per-graph forward: owner-computes, zero LDS atomics ----------------
__global__ void __launch_bounds__(1024, 1)
k_fused(const float* __restrict__ state, const float* __restrict__ rw,
        const float* __restrict__ code_emb, const float* __restrict__ h_bias,
        const float* __restrict__ be, const float* __restrict__ attn_h,
        const float* __restrict__ attn_t, const int* __restrict__ node_ids,
        const int* __restrict__ curs, const int* __restrict__ smeta,
        const float* __restrict__ prep, const uint4* __restrict__ wf,
        float* __restrict__ xout, float* __restrict__ relOut, float* __restrict__ edgeOut) {
    extern __shared__ char smem[];
    __half* hH  = (__half*)(smem + S_H);
    __half* hpH = (__half*)(smem + S_HP);
    __half* Uh  = (__half*)(smem + S_U);
    float* ehp  = (float*)(smem + S_EH);
    float* etp  = (float*)(smem + S_ET);
    float* denp = (float*)(smem + S_DEN);
    float* rap  = (float*)(smem + S_RA);
    float* esgp = (float*)(smem + S_ESG);
    float* sAH  = (float*)(smem + S_AH);
    float* sAT  = (float*)(smem + S_AT);
    int*   mlds = (int*)(smem + S_MLDS);
    int*   rp   = (int*)(smem + S_RP);
    const uint4* wfe = wf + 4096;

    const int g = blockIdx.x;
    const int t = threadIdx.x;
    const int lane = t & 63, w = t >> 6;          // 16 waves
    const int ln15 = lane & 15, q = lane >> 4, q8 = q << 3;
    const int MtA = w % 7, NtA = w / 7;
    const bool hasT = (w < 14);
    const int cg = w >> 1;
    const int colc = cg * 16 + ln15;
    const int physc = (colc & 3) * 32 + (colc >> 2);
    const int Mt0 = (w & 1) ? 4 : 0;
    const int Mt1 = (w & 1) ? 7 : 4;

    // P0: h0 = code_emb[node_ids]; rowptr scan; CSR stage
    for (int i = t; i < 1600; i += 1024) {
        int n = i >> 4, dp = i & 15;
        int id = node_ids[g * 100 + n];
        float2 v = *(const float2*)&code_emb[(size_t)id * 32 + dp * 2];
        *(__half2*)&hH[n * 40 + dp * 2] = __floats2half2_rn(v.x, v.y);
    }
    if (t < 100) { int c = curs[g * 100 + t]; rp[t + 1] = c < CAP ? c : CAP; }
    if (t == 0) rp[0] = 0;
    __syncthreads();
    for (int o = 1; o < 128; o <<= 1) {
        int v = 0;
        if (t <= 100 && t >= o) v = rp[t - o];
        __syncthreads();
        if (t <= 100 && t >= o) rp[t] += v;
        __syncthreads();
    }
    for (int i = t; i < 100 * CAP; i += 1024) {
        int bin = i / CAP, pos = i % CAP;
        int lo = rp[bin], cnt = rp[bin + 1] - lo;
        if (pos < cnt)
            mlds[lo + pos] = smeta[(size_t)(g * 100 + bin) * CAP + pos];
    }

    for (int l = 0; l < 2; ++l) {
        __syncthreads();   // B0: h/CSR ready, U free

        // ---- X1: zero U; stage sAH/sAT; MFMA hp = h@We + be; P1 rel-att ----
        for (int i = t; i < 6450; i += 1024) ((uint4*)(smem + S_U))[i] = make_uint4(0, 0, 0, 0);
        if (t < 128) {
            sAH[t] = attn_h[l * 128 + (t & 3) * 32 + (t >> 2)];
            sAT[t] = attn_t[l * 128 + (t & 3) * 32 + (t >> 2)];
        }
        {
            uint4 bwe = wfe[(l * 8 + cg) * 64 + lane];
            f16x8 bw = u4_to_f16x8(bwe);
            float beC = be[l * 128 + physc];
            f32x4 z = {0.f, 0.f, 0.f, 0.f};
            for (int Mt = Mt0; Mt < Mt1; ++Mt) {
                const __half* hr = hH + (Mt * 16 + ln15) * 40 + q8;
                f32x4 pc = __builtin_amdgcn_mfma_f32_16x16x32_f16(
                    two_u2(*(const uint2*)hr, *(const uint2*)(hr + 4)), bw, z, 0, 0, 0);
                #pragma unroll
                for (int i = 0; i < 4; ++i) {
                    int n = Mt * 16 + q * 4 + i;
                    if (n < 100) hpH[hpIdx(n, colc)] = __float2half(pc[i] + beC);
                }
            }
        }
        {   // P1: relation attention (all waves redundantly; benign identical writes)
            int k32 = lane & 31;
            float sG = state[g * 32 + k32];
            float4 frs = *(const float4*)&prep[128 + l * 128 + k32 * 4];
            float4 fes = *(const float4*)&prep[384 + l * 128 + k32 * 4];
            float p0 = sG * frs.x, p1 = sG * frs.y, p2 = sG * frs.z, p3 = sG * frs.w;
            float q0 = sG * fes.x, q1 = sG * fes.y, q2 = sG * fes.z, q3 = sG * fes.w;
            #pragma unroll
            for (int m = 1; m < 32; m <<= 1) {
                p0 += __shfl_xor(p0, m); p1 += __shfl_xor(p1, m);
                p2 += __shfl_xor(p2, m); p3 += __shfl_xor(p3, m);
                q0 += __shfl_xor(q0, m); q1 += __shfl_xor(q1, m);
                q2 += __shfl_xor(q2, m); q3 += __shfl_xor(q3, m);
            }
            int h = lane & 3;
            float esh  = (h & 2) ? ((h & 1) ? p3 : p2) : ((h & 1) ? p1 : p0);
            float esgh = (h & 2) ? ((h & 1) ? q3 : q2) : ((h & 1) ? q1 : q0);
            esh  += prep[640 + l * 4 + h];
            esgh += prep[648 + l * 4 + h];
            if (lane < 4) esgp[lane] = esgh;
            float er = prep[l * 64 + lane];
            float ex = __expf(lrelu(er + esh));
            float s = ex;
            s += __shfl_xor(s, 4); s += __shfl_xor(s, 8);
            s += __shfl_xor(s, 16); s += __shfl_xor(s, 32);
            rap[lane] = ex / s;
        }
        __syncthreads();   // B1: hp/sAH/sAT/rap/esg ready, U zeroed

        // ---- A0: eh/et per src node (owner = s; no atomics) ----
        if (t < 100) {
            int s = t;
            int sw = (s & 7) << 3;
            float eh[4] = {0, 0, 0, 0}, et[4] = {0, 0, 0, 0};
            #pragma unroll 4
            for (int i = 0; i < 16; ++i) {
                uint4 hv = *(const uint4*)&hpH[s * 128 + ((i * 8) ^ sw)];
                unsigned short hu[8];
                __builtin_memcpy(hu, &hv, 16);
                #pragma unroll
                for (int k = 0; k < 8; ++k) {
                    float f = h2f(hu[k]);
                    eh[k & 3] += f * sAH[i * 8 + k];
                    et[k & 3] += f * sAT[i * 8 + k];
                }
            }
            *(float4*)&ehp[s * 4] = make_float4(eh[0], eh[1], eh[2], eh[3]);
            *(float4*)&etp[s * 4] = make_float4(et[0], et[1], et[2], et[3]);
        }
        __syncthreads();   // B1b: eh/et ready

        // ---- A: den per (dst, head) (owner; no atomics) + attention outputs ----
        if (t < 400) {
            int d = t >> 2, h = t & 3;
            int lo = rp[d], hi = rp[d + 1];
            float etd = etp[d * 4 + h] + esgp[h];
            float den = 0.f;
            for (int e = lo; e < hi; ++e) {
                int m = mlds[e];
                den += __expf(lrelu(ehp[(m & 127) * 4 + h] + etd));
            }
            denp[d * 4 + h] = den;
            if (l == 1) {
                float inv = 1.f / den;
                for (int e = lo; e < hi; ++e) {
                    int m = mlds[e];
                    float x = __expf(lrelu(ehp[(m & 127) * 4 + h] + etd));
                    int oe = (m >> 11) & 0xFFFFF;
                    int r = (m >> 7) & 15;
                    edgeOut[(size_t)oe * 4 + h] = x * inv;
                    relOut[(size_t)oe * 4 + h] = rap[r * 4 + h];
                }
            }
        }
        __syncthreads();   // B2: den ready

        // ---- B: U accumulation per (dst, dim-quad) (owner; plain RMW, no atomics) ----
        if (t < 800) {
            int d = t >> 3, j = t & 7;          // dims [j*4, j*4+4)
            int lo = rp[d], hi = rp[d + 1];
            float4 et4 = *(const float4*)&etp[d * 4];
            float4 esg4 = *(const float4*)esgp;
            float e0 = et4.x + esg4.x, e1 = et4.y + esg4.y;
            float e2 = et4.z + esg4.z, e3 = et4.w + esg4.w;
            float4 dn = *(const float4*)&denp[d * 4];
            float i0 = 1.f / dn.x, i1 = 1.f / dn.y, i2 = 1.f / dn.z, i3 = 1.f / dn.w;
            for (int e = lo; e < hi; ++e) {
                int m = mlds[e];
                int s = m & 127, r = (m >> 7) & 15;
                float4 eh4 = *(const float4*)&ehp[s * 4];
                float4 r4 = *(const float4*)&rap[r * 4];
                float c0 = __expf(lrelu(eh4.x + e0)) * i0 * r4.x;
                float c1 = __expf(lrelu(eh4.y + e1)) * i1 * r4.y;
                float c2 = __expf(lrelu(eh4.z + e2)) * i2 * r4.z;
                float c3 = __expf(lrelu(eh4.w + e3)) * i3 * r4.w;
                int sw = (s & 7) << 3;
                uint4 hv0 = *(const uint4*)&hpH[s * 128 + ((j * 16) ^ sw)];
                uint4 hv1 = *(const uint4*)&hpH[s * 128 + ((j * 16 + 8) ^ sw)];
                unsigned short hu[16];
                __builtin_memcpy(hu, &hv0, 16);
                __builtin_memcpy(hu + 8, &hv1, 16);
                float v0 = c0*h2f(hu[0])  + c1*h2f(hu[1])  + c2*h2f(hu[2])  + c3*h2f(hu[3]);
                float v1 = c0*h2f(hu[4])  + c1*h2f(hu[5])  + c2*h2f(hu[6])  + c3*h2f(hu[7]);
                float v2 = c0*h2f(hu[8])  + c1*h2f(hu[9])  + c2*h2f(hu[10]) + c3*h2f(hu[11]);
                float v3 = c0*h2f(hu[12]) + c1*h2f(hu[13]) + c2*h2f(hu[14]) + c3*h2f(hu[15]);
                __half* up = Uh + d * UROW + r * 32 + j * 4;
                __half2 u01 = *(__half2*)up;
                __half2 u23 = *(__half2*)(up + 2);
                float2 f01 = __half22float2(u01), f23 = __half22float2(u23);
                *(__half2*)up       = __floats2half2_rn(f01.x + v0, f01.y + v1);
                *(__half2*)(up + 2) = __floats2half2_rn(f23.x + v2, f23.y + v3);
            }
        }
        __syncthreads();   // B3: U complete

        // ---- P7: 16-relation MFMA chain (waves 0..13) ----
        f32x4 accA = {0.f, 0.f, 0.f, 0.f};
        if (hasT) {
            #pragma unroll 4
            for (int rel = 0; rel < 16; ++rel) {
                uint4 bAu = wf[((l * 16 + rel) * 2 + NtA) * 64 + lane];
                const __half* up = Uh + (MtA * 16 + ln15) * UROW + rel * 32 + q8;
                f16x8 af = two_u2(*(const uint2*)up, *(const uint2*)(up + 4));
                accA = __builtin_amdgcn_mfma_f32_16x16x32_f16(af, u4_to_f16x8(bAu), accA, 0, 0, 0);
            }
        }
        // P8: h = relu(0.5*(agg+bias) + 0.5*h)
        if (hasT) {
            int dcol = NtA * 16 + ln15;
            float bias = h_bias[l * 32 + dcol];
            #pragma unroll
            for (int i = 0; i < 4; ++i) {
                int n = MtA * 16 + q * 4 + i;
                if (n < 100) {
                    float hold = __half2float(hH[n * 40 + dcol]);
                    float hn = fmaxf(0.f, 0.5f * (accA[i] + bias) + 0.5f * hold);
                    hH[n * 40 + dcol] = __float2half(hn);
                }
            }
        }
    }
    __syncthreads();   // h final

    // P9: readout x[g] = sum_n h[n] * rw[n]   (red buffer reuses U region)
    float* redp = (float*)(smem + S_U);
    {
        int part = t >> 5, d = t & 31;
        float acc = 0.f;
        for (int n = part; n < 100; n += 32)
            acc += __half2float(hH[n * 40 + d]) * rw[g * 100 + n];
        redp[part * 32 + d] = acc;
    }
    __syncthreads();
    if (t < 32) {
        float s = 0.f;
        #pragma unroll
        for (int p = 0; p < 32; ++p) s += redp[p * 32 + t];
        xout[g * 32 + t] = s;
    }
}

extern "C" void kernel_launch(void* const* d_in, const int* in_sizes, int n_in,
                              void* d_out, int out_size, void* d_ws, size_t ws_size,
                              hipStream_t stream) {
    const float* state     = (const float*)d_in[0];
    const float* rw        = (const float*)d_in[1];
    const float* code_emb  = (const float*)d_in[2];
    const float* rel_table = (const float*)d_in[3];
    const float* W         = (const float*)d_in[4];
    const float* h_bias    = (const float*)d_in[5];
    const float* Wr        = (const float*)d_in[6];
    const float* br        = (const float*)d_in[7];
    const float* We        = (const float*)d_in[8];
    const float* be        = (const float*)d_in[9];
    const float* attn_h    = (const float*)d_in[10];
    const float* attn_t    = (const float*)d_in[11];
    const float* attn_s    = (const float*)d_in[12];
    const float* attn_r    = (const float*)d_in[13];
    const float* attn_rs   = (const float*)d_in[14];
    const int* node_ids    = (const int*)d_in[15];
    const int* src         = (const int*)d_in[16];
    const int* dst         = (const int*)d_in[17];
    const int* rtype       = (const int*)d_in[18];

    float* out = (float*)d_out;
    float* xout = out;
    float* relOut = out + (size_t)NGRAPH * 32;
    float* edgeOut = relOut + (size_t)EDGES * 4;

    int* wsi = (int*)d_ws;
    float* wsf = (float*)d_ws;
    int* curs   = wsi + WI_CURS;
    int* smeta  = wsi + WI_SMETA;
    float* prep = wsf + WF_PREP;
    uint4* wfrag = (uint4*)(wsf + WF_WFRAG);

    (void)hipMemsetAsync(curs, 0, NNODE * sizeof(int), stream);
    k_scatter<<<(EDGES + 255) / 256, 256, 0, stream>>>(src, dst, rtype, curs, smeta);
    k_setup<<<21, 256, 0, stream>>>(rel_table, Wr, br, We, be, attn_r, attn_rs, attn_s,
                                    W, prep, wfrag);

    (void)hipFuncSetAttribute((const void*)k_fused, hipFuncAttributeMaxDynamicSharedMemorySize, S_TOTAL);
    k_fused<<<NGRAPH, 1024, S_TOTAL, stream>>>(state, rw, code_emb, h_bias, be,
                                               attn_h, attn_t, node_ids, curs, smeta,
                                               prep, wfrag, xout, relOut, edgeOut);
}

// Round 16
// 173.287 us; speedup vs baseline: 2.0828x; 1.1298x over previous
//
#include <hip/hip_runtime.h>
#include <hip/hip_fp16.h>

#define DI __device__ __forceinline__

constexpr int NGRAPH = 500;
constexpr int EDGES  = 800000;
constexpr int NNODE  = 50000;
constexpr int CAP    = 56;            // slots per dst bin (Poisson mean 16, 10 sigma)
constexpr int SCAT_BLOCKS = (EDGES + 255) / 256;   // 3125

// ---- workspace layout (4-byte units) ----
constexpr size_t WI_CURS  = 0;                          // [50000]
constexpr size_t WI_SMETA = 50048;                      // [50000*56]
constexpr size_t WF_PREP  = WI_SMETA + (size_t)NNODE * CAP;  // 656 floats (pad 672)
constexpr size_t WF_WFRAG = WF_PREP + 672;              // uint4[5120]

// ---- LDS layout (bytes), total 151496 -> 1 block/CU ----
constexpr int S_H    = 0;        // f16 h[100][40] (cols 0..31 used)
constexpr int S_HP   = 8000;     // f16 hp[100][128] (col c -> d=c>>2,h=c&3), XOR-swizzled
constexpr int S_U    = 33600;    // f16 U[100][516]
constexpr int S_EH   = 136800;   // f32[100][4]
constexpr int S_ET   = 138400;   // f32[100][4]
constexpr int S_DEN  = 140000;   // f32[100][4]
constexpr int S_RA   = 141600;   // f32[16][4]
constexpr int S_ESG  = 141856;   // f32[4]
constexpr int S_AH   = 141872;   // f32[128] attn_h in hp-col order
constexpr int S_AT   = 142384;   // f32[128]
constexpr int S_MLDS = 142896;   // i32[2048] dst-sorted edge meta
constexpr int S_RP   = 151088;   // i32[102] rowptr
constexpr int S_TOTAL = 151496;
constexpr int UROW = 516;

typedef _Float16 f16x8 __attribute__((ext_vector_type(8)));
typedef _Float16 f16x2 __attribute__((ext_vector_type(2)));
typedef float f32x4 __attribute__((ext_vector_type(4)));

DI float lrelu(float x) { return x >= 0.f ? x : 0.2f * x; }
DI f16x8 u4_to_f16x8(uint4 u) { f16x8 r; __builtin_memcpy(&r, &u, 16); return r; }
DI f16x8 two_u2(uint2 a, uint2 b) { return u4_to_f16x8(make_uint4(a.x, a.y, b.x, b.y)); }
DI float h2f(unsigned short u) { __half hv; __builtin_memcpy(&hv, &u, 2); return __half2float(hv); }

// f32 += half2 . half2 via v_dot2_f32_f16
DI float fdot2u(unsigned a, unsigned b, float c) {
    f16x2 av, bv;
    __builtin_memcpy(&av, &a, 4);
    __builtin_memcpy(&bv, &b, 4);
    return __builtin_amdgcn_fdot2(av, bv, c, false);
}

// hp swizzle: half-index for (node n, col c); XOR bits 3..5 with n&7 (16B granularity)
DI int hpIdx(int n, int c) { return n * 128 + (c ^ ((n & 7) << 3)); }

// ---------------- merged prep: scatter-by-dst + prep folds + MFMA fragments ----------------
__global__ void k_prep(const int* __restrict__ src, const int* __restrict__ dst,
                       const int* __restrict__ rt, int* __restrict__ curs,
                       int* __restrict__ smeta,
                       const float* __restrict__ rel_table, const float* __restrict__ Wr,
                       const float* __restrict__ br, const float* __restrict__ We,
                       const float* __restrict__ be, const float* __restrict__ attn_r,
                       const float* __restrict__ attn_rs, const float* __restrict__ attn_s,
                       const float* __restrict__ W, float* __restrict__ prep,
                       uint4* __restrict__ wf) {
    __shared__ float wra[2][32][4];
    __shared__ float sbias[2][3][4];
    int bb = blockIdx.x, t = threadIdx.x;
    if (bb < SCAT_BLOCKS) {
        int e = bb * 256 + t;
        if (e >= EDGES) return;
        int s = src[e], d = dst[e], r = rt[e];
        int g = (unsigned)d / 100u;
        int pos = atomicAdd(&curs[d], 1);
        if (pos < CAP)
            smeta[(size_t)d * CAP + pos] = (s - g * 100) | (r << 7) | (e << 11);
        return;
    }
    int b = bb - SCAT_BLOCKS;
    if (b == 0) {
        {
            int l = t >> 7, k = (t >> 2) & 31, h = t & 3;
            float a = 0.f, b2 = 0.f, c = 0.f;
            for (int d2 = 0; d2 < 32; ++d2) {
                float w1 = Wr[(size_t)(l*32 + k)*128 + h*32 + d2];
                float w2 = We[(size_t)(l*32 + k)*128 + h*32 + d2];
                a  += w1 * attn_r [l*128 + h*32 + d2];
                b2 += w1 * attn_rs[l*128 + h*32 + d2];
                c  += w2 * attn_s [l*128 + h*32 + d2];
            }
            wra[l][k][h] = a;
            prep[128 + (l*32 + k)*4 + h] = b2;
            prep[384 + (l*32 + k)*4 + h] = c;
        }
        if (t < 24) {
            int l = t / 12, which = (t % 12) / 4, h = t % 4;
            const float* bp = (which == 2) ? be : br;
            const float* ap = (which == 0) ? attn_r : (which == 1 ? attn_rs : attn_s);
            float s = 0.f;
            for (int d2 = 0; d2 < 32; ++d2) s += bp[l*128 + h*32 + d2] * ap[l*128 + h*32 + d2];
            sbias[l][which][h] = s;
        }
        __syncthreads();
        if (t < 128) {
            int l = t >> 6, r = (t >> 2) & 15, h = t & 3;
            float s = sbias[l][0][h];
            for (int k = 0; k < 32; ++k) s += rel_table[r*32 + k] * wra[l][k][h];
            prep[(l*16 + r)*4 + h] = s;
        }
        if (t < 8) {
            int l = t >> 2, h = t & 3;
            prep[640 + l*4 + h] = sbias[l][1][h];
            prep[648 + l*4 + h] = sbias[l][2][h];
        }
    } else if (b <= 16) {
        // W fragments (f16): wf[((l*16+rel)*2+Nt)*64 + ln]
        int fi = (b - 1) * 256 + t;
        int ln = fi & 63, Nt = (fi >> 6) & 1, rel = (fi >> 7) & 15, l = fi >> 11;
        int j = Nt*16 + (ln & 15), k0 = (ln >> 4) << 3;
        unsigned short fr[8];
        #pragma unroll
        for (int i = 0; i < 8; ++i) {
            __half hv = __float2half(W[(((size_t)l*16 + rel)*32 + k0 + i)*32 + j]);
            __builtin_memcpy(&fr[i], &hv, 2);
        }
        uint4 o;
        o.x = fr[0] | ((unsigned)fr[1] << 16);
        o.y = fr[2] | ((unsigned)fr[3] << 16);
        o.z = fr[4] | ((unsigned)fr[5] << 16);
        o.w = fr[6] | ((unsigned)fr[7] << 16);
        wf[fi] = o;
    } else {
        // We fragments (f16, column-permuted): col c -> phys (c&3)*32+(c>>2)
        int fi = (b - 17) * 256 + t;
        int ln = fi & 63, Nt = (fi >> 6) & 7, l = fi >> 9;
        int c = Nt*16 + (ln & 15);
        int phys = (c & 3)*32 + (c >> 2);
        int k0 = (ln >> 4) << 3;
        unsigned short fr[8];
        #pragma unroll
        for (int i = 0; i < 8; ++i) {
            __half hv = __float2half(We[(size_t)l*4096 + (k0 + i)*128 + phys]);
            __builtin_memcpy(&fr[i], &hv, 2);
        }
        uint4 o;
        o.x = fr[0] | ((unsigned)fr[1] << 16);
        o.y = fr[2] | ((unsigned)fr[3] << 16);
        o.z = fr[4] | ((unsigned)fr[5] << 16);
        o.w = fr[6] | ((unsigned)fr[7] << 16);
        wf[4096 + fi] = o;
    }
}

// ---------------- fused per-graph forward: owner-computes, zero LDS atomics ----------------
__global__ void __launch_bounds__(1024, 1)
k_fused(const float* __restrict__ state, const float* __restrict__ rw,
        const float* __restrict__ code_emb, const float* __restrict__ h_bias,
        const float* __restrict__ be, const float* __restrict__ attn_h,
        const float* __restrict__ attn_t, const int* __restrict__ node_ids,
        const int* __restrict__ curs, const int* __restrict__ smeta,
        const float* __restrict__ prep, const uint4* __restrict__ wf,
        float* __restrict__ xout, float* __restrict__ relOut, float* __restrict__ edgeOut) {
    extern __shared__ char smem[];
    __half* hH  = (__half*)(smem + S_H);
    __half* hpH = (__half*)(smem + S_HP);
    __half* Uh  = (__half*)(smem + S_U);
    float* ehp  = (float*)(smem + S_EH);
    float* etp  = (float*)(smem + S_ET);
    float* denp = (float*)(smem + S_DEN);
    float* rap  = (float*)(smem + S_RA);
    float* esgp = (float*)(smem + S_ESG);
    float* sAH  = (float*)(smem + S_AH);
    float* sAT  = (float*)(smem + S_AT);
    int*   mlds = (int*)(smem + S_MLDS);
    int*   rp   = (int*)(smem + S_RP);
    const uint4* wfe = wf + 4096;

    const int g = blockIdx.x;
    const int t = threadIdx.x;
    const int lane = t & 63, w = t >> 6;          // 16 waves
    const int ln15 = lane & 15, q = lane >> 4, q8 = q << 3;
    const int MtA = w % 7, NtA = w / 7;
    const bool hasT = (w < 14);
    const int cg = w >> 1;
    const int colc = cg * 16 + ln15;
    const int physc = (colc & 3) * 32 + (colc >> 2);
    const int Mt0 = (w & 1) ? 4 : 0;
    const int Mt1 = (w & 1) ? 7 : 4;

    // P0: h0 = code_emb[node_ids]; rowptr scan; CSR stage
    for (int i = t; i < 1600; i += 1024) {
        int n = i >> 4, dp = i & 15;
        int id = node_ids[g * 100 + n];
        float2 v = *(const float2*)&code_emb[(size_t)id * 32 + dp * 2];
        *(__half2*)&hH[n * 40 + dp * 2] = __floats2half2_rn(v.x, v.y);
    }
    if (t < 100) { int c = curs[g * 100 + t]; rp[t + 1] = c < CAP ? c : CAP; }
    if (t == 0) rp[0] = 0;
    __syncthreads();
    for (int o = 1; o < 128; o <<= 1) {
        int v = 0;
        if (t <= 100 && t >= o) v = rp[t - o];
        __syncthreads();
        if (t <= 100 && t >= o) rp[t] += v;
        __syncthreads();
    }
    for (int i = t; i < 100 * CAP; i += 1024) {
        int bin = i / CAP, pos = i % CAP;
        int lo = rp[bin], cnt = rp[bin + 1] - lo;
        if (pos < cnt)
            mlds[lo + pos] = smeta[(size_t)(g * 100 + bin) * CAP + pos];
    }

    for (int l = 0; l < 2; ++l) {
        __syncthreads();   // B0: h/CSR ready, U free

        // ---- X1: zero U; stage sAH/sAT; MFMA hp = h@We + be; P1 rel-att ----
        for (int i = t; i < 6450; i += 1024) ((uint4*)(smem + S_U))[i] = make_uint4(0, 0, 0, 0);
        if (t < 128) {
            sAH[t] = attn_h[l * 128 + (t & 3) * 32 + (t >> 2)];
            sAT[t] = attn_t[l * 128 + (t & 3) * 32 + (t >> 2)];
        }
        {
            uint4 bwe = wfe[(l * 8 + cg) * 64 + lane];
            f16x8 bw = u4_to_f16x8(bwe);
            float beC = be[l * 128 + physc];
            f32x4 z = {0.f, 0.f, 0.f, 0.f};
            for (int Mt = Mt0; Mt < Mt1; ++Mt) {
                const __half* hr = hH + (Mt * 16 + ln15) * 40 + q8;
                f32x4 pc = __builtin_amdgcn_mfma_f32_16x16x32_f16(
                    two_u2(*(const uint2*)hr, *(const uint2*)(hr + 4)), bw, z, 0, 0, 0);
                #pragma unroll
                for (int i = 0; i < 4; ++i) {
                    int n = Mt * 16 + q * 4 + i;
                    if (n < 100) hpH[hpIdx(n, colc)] = __float2half(pc[i] + beC);
                }
            }
        }
        {   // P1: relation attention (all waves redundantly; benign identical writes)
            int k32 = lane & 31;
            float sG = state[g * 32 + k32];
            float4 frs = *(const float4*)&prep[128 + l * 128 + k32 * 4];
            float4 fes = *(const float4*)&prep[384 + l * 128 + k32 * 4];
            float p0 = sG * frs.x, p1 = sG * frs.y, p2 = sG * frs.z, p3 = sG * frs.w;
            float q0 = sG * fes.x, q1 = sG * fes.y, q2 = sG * fes.z, q3 = sG * fes.w;
            #pragma unroll
            for (int m = 1; m < 32; m <<= 1) {
                p0 += __shfl_xor(p0, m); p1 += __shfl_xor(p1, m);
                p2 += __shfl_xor(p2, m); p3 += __shfl_xor(p3, m);
                q0 += __shfl_xor(q0, m); q1 += __shfl_xor(q1, m);
                q2 += __shfl_xor(q2, m); q3 += __shfl_xor(q3, m);
            }
            int h = lane & 3;
            float esh  = (h & 2) ? ((h & 1) ? p3 : p2) : ((h & 1) ? p1 : p0);
            float esgh = (h & 2) ? ((h & 1) ? q3 : q2) : ((h & 1) ? q1 : q0);
            esh  += prep[640 + l * 4 + h];
            esgh += prep[648 + l * 4 + h];
            if (lane < 4) esgp[lane] = esgh;
            float er = prep[l * 64 + lane];
            float ex = __expf(lrelu(er + esh));
            float s = ex;
            s += __shfl_xor(s, 4); s += __shfl_xor(s, 8);
            s += __shfl_xor(s, 16); s += __shfl_xor(s, 32);
            rap[lane] = ex / s;
        }
        __syncthreads();   // B1: hp/sAH/sAT/rap/esg ready, U zeroed

        // ---- A0: eh/et per src node (owner = s; no atomics) ----
        if (t < 100) {
            int s = t;
            int sw = (s & 7) << 3;
            float eh[4] = {0, 0, 0, 0}, et[4] = {0, 0, 0, 0};
            #pragma unroll 4
            for (int i = 0; i < 16; ++i) {
                uint4 hv = *(const uint4*)&hpH[s * 128 + ((i * 8) ^ sw)];
                unsigned short hu[8];
                __builtin_memcpy(hu, &hv, 16);
                #pragma unroll
                for (int k = 0; k < 8; ++k) {
                    float f = h2f(hu[k]);
                    eh[k & 3] += f * sAH[i * 8 + k];
                    et[k & 3] += f * sAT[i * 8 + k];
                }
            }
            *(float4*)&ehp[s * 4] = make_float4(eh[0], eh[1], eh[2], eh[3]);
            *(float4*)&etp[s * 4] = make_float4(et[0], et[1], et[2], et[3]);
        }
        __syncthreads();   // B1b: eh/et ready

        // ---- A: den per (dst, head) (owner; no atomics) ----
        if (t < 400) {
            int d = t >> 2, h = t & 3;
            int lo = rp[d], hi = rp[d + 1];
            float etd = etp[d * 4 + h] + esgp[h];
            float den = 0.f;
            for (int e = lo; e < hi; ++e) {
                int m = mlds[e];
                den += __expf(lrelu(ehp[(m & 127) * 4 + h] + etd));
            }
            denp[d * 4 + h] = den;
        }
        __syncthreads();   // B2: den ready

        // ---- B: U accumulation per (dst, dim-quad) (owner; fdot2 + pk_add, no atomics) ----
        if (t < 800) {
            int d = t >> 3, j = t & 7;          // dims [j*4, j*4+4)
            int lo = rp[d], hi = rp[d + 1];
            float4 et4 = *(const float4*)&etp[d * 4];
            float4 esg4 = *(const float4*)esgp;
            float e0 = et4.x + esg4.x, e1 = et4.y + esg4.y;
            float e2 = et4.z + esg4.z, e3 = et4.w + esg4.w;
            float4 dn = *(const float4*)&denp[d * 4];
            float i0 = 1.f / dn.x, i1 = 1.f / dn.y, i2 = 1.f / dn.z, i3 = 1.f / dn.w;
            bool wAtt = (l == 1) && (j == 0);
            for (int e = lo; e < hi; ++e) {
                int m = mlds[e];
                int s = m & 127, r = (m >> 7) & 15;
                float4 eh4 = *(const float4*)&ehp[s * 4];
                float4 r4 = *(const float4*)&rap[r * 4];
                float a0 = __expf(lrelu(eh4.x + e0)) * i0;
                float a1 = __expf(lrelu(eh4.y + e1)) * i1;
                float a2 = __expf(lrelu(eh4.z + e2)) * i2;
                float a3 = __expf(lrelu(eh4.w + e3)) * i3;
                if (wAtt) {
                    int oe = (m >> 11) & 0xFFFFF;
                    *(float4*)&edgeOut[(size_t)oe * 4] = make_float4(a0, a1, a2, a3);
                    *(float4*)&relOut[(size_t)oe * 4] = r4;
                }
                __half2 c01h = __floats2half2_rn(a0 * r4.x, a1 * r4.y);
                __half2 c23h = __floats2half2_rn(a2 * r4.z, a3 * r4.w);
                unsigned uc01, uc23;
                __builtin_memcpy(&uc01, &c01h, 4);
                __builtin_memcpy(&uc23, &c23h, 4);
                int sw = (s & 7) << 3;
                uint4 hv0 = *(const uint4*)&hpH[s * 128 + ((j * 16) ^ sw)];
                uint4 hv1 = *(const uint4*)&hpH[s * 128 + ((j * 16 + 8) ^ sw)];
                float v0 = fdot2u(uc01, hv0.x, fdot2u(uc23, hv0.y, 0.f));
                float v1 = fdot2u(uc01, hv0.z, fdot2u(uc23, hv0.w, 0.f));
                float v2 = fdot2u(uc01, hv1.x, fdot2u(uc23, hv1.y, 0.f));
                float v3 = fdot2u(uc01, hv1.z, fdot2u(uc23, hv1.w, 0.f));
                __half2 v01 = __floats2half2_rn(v0, v1);
                __half2 v23 = __floats2half2_rn(v2, v3);
                __half2* up = (__half2*)(Uh + d * UROW + r * 32 + j * 4);
                up[0] = __hadd2(up[0], v01);
                up[1] = __hadd2(up[1], v23);
            }
        }
        __syncthreads();   // B3: U complete

        // ---- P7: 16-relation MFMA chain (waves 0..13) ----
        f32x4 accA = {0.f, 0.f, 0.f, 0.f};
        if (hasT) {
            #pragma unroll 4
            for (int rel = 0; rel < 16; ++rel) {
                uint4 bAu = wf[((l * 16 + rel) * 2 + NtA) * 64 + lane];
                const __half* up = Uh + (MtA * 16 + ln15) * UROW + rel * 32 + q8;
                f16x8 af = two_u2(*(const uint2*)up, *(const uint2*)(up + 4));
                accA = __builtin_amdgcn_mfma_f32_16x16x32_f16(af, u4_to_f16x8(bAu), accA, 0, 0, 0);
            }
        }
        // P8: h = relu(0.5*(agg+bias) + 0.5*h)
        if (hasT) {
            int dcol = NtA * 16 + ln15;
            float bias = h_bias[l * 32 + dcol];
            #pragma unroll
            for (int i = 0; i < 4; ++i) {
                int n = MtA * 16 + q * 4 + i;
                if (n < 100) {
                    float hold = __half2float(hH[n * 40 + dcol]);
                    float hn = fmaxf(0.f, 0.5f * (accA[i] + bias) + 0.5f * hold);
                    hH[n * 40 + dcol] = __float2half(hn);
                }
            }
        }
    }
    __syncthreads();   // h final

    // P9: readout x[g] = sum_n h[n] * rw[n]   (red buffer reuses U region)
    float* redp = (float*)(smem + S_U);
    {
        int part = t >> 5, d = t & 31;
        float acc = 0.f;
        for (int n = part; n < 100; n += 32)
            acc += __half2float(hH[n * 40 + d]) * rw[g * 100 + n];
        redp[part * 32 + d] = acc;
    }
    __syncthreads();
    if (t < 32) {
        float s = 0.f;
        #pragma unroll
        for (int p = 0; p < 32; ++p) s += redp[p * 32 + t];
        xout[g * 32 + t] = s;
    }
}

extern "C" void kernel_launch(void* const* d_in, const int* in_sizes, int n_in,
                              void* d_out, int out_size, void* d_ws, size_t ws_size,
                              hipStream_t stream) {
    const float* state     = (const float*)d_in[0];
    const float* rw        = (const float*)d_in[1];
    const float* code_emb  = (const float*)d_in[2];
    const float* rel_table = (const float*)d_in[3];
    const float* W         = (const float*)d_in[4];
    const float* h_bias    = (const float*)d_in[5];
    const float* Wr        = (const float*)d_in[6];
    const float* br        = (const float*)d_in[7];
    const float* We        = (const float*)d_in[8];
    const float* be        = (const float*)d_in[9];
    const float* attn_h    = (const float*)d_in[10];
    const float* attn_t    = (const float*)d_in[11];
    const float* attn_s    = (const float*)d_in[12];
    const float* attn_r    = (const float*)d_in[13];
    const float* attn_rs   = (const float*)d_in[14];
    const int* node_ids    = (const int*)d_in[15];
    const int* src         = (const int*)d_in[16];
    const int* dst         = (const int*)d_in[17];
    const int* rtype       = (const int*)d_in[18];

    float* out = (float*)d_out;
    float* xout = out;
    float* relOut = out + (size_t)NGRAPH * 32;
    float* edgeOut = relOut + (size_t)EDGES * 4;

    int* wsi = (int*)d_ws;
    float* wsf = (float*)d_ws;
    int* curs   = wsi + WI_CURS;
    int* smeta  = wsi + WI_SMETA;
    float* prep = wsf + WF_PREP;
    uint4* wfrag = (uint4*)(wsf + WF_WFRAG);

    (void)hipMemsetAsync(curs, 0, NNODE * sizeof(int), stream);
    k_prep<<<SCAT_BLOCKS + 21, 256, 0, stream>>>(src, dst, rtype, curs, smeta,
                                                 rel_table, Wr, br, We, be,
                                                 attn_r, attn_rs, attn_s, W, prep, wfrag);

    (void)hipFuncSetAttribute((const void*)k_fused, hipFuncAttributeMaxDynamicSharedMemorySize, S_TOTAL);
    k_fused<<<NGRAPH, 1024, S_TOTAL, stream>>>(state, rw, code_emb, h_bias, be,
                                               attn_h, attn_t, node_ids, curs, smeta,
                                               prep, wfrag, xout, relOut, edgeOut);
}

// Round 17
// 169.623 us; speedup vs baseline: 2.1278x; 1.0216x over previous
//
#include <hip/hip_runtime.h>
#include <hip/hip_fp16.h>

#define DI __device__ __forceinline__

constexpr int NGRAPH = 500;
constexpr int EDGES  = 800000;
constexpr int NNODE  = 50000;
constexpr int CAP    = 64;            // slots per dst bin (Poisson mean 16; pow2 for shifts)
constexpr int SCAT_BLOCKS = (EDGES + 255) / 256;   // 3125

// ---- workspace layout (4-byte units) ----
constexpr size_t WI_CURS  = 0;                               // [50000]
constexpr size_t WI_SMETA = 50048;                           // [50000*64]
constexpr size_t WF_PREP  = WI_SMETA + (size_t)NNODE * CAP;  // 656 floats (pad 672)
constexpr size_t WF_WFRAG = WF_PREP + 672;                   // uint4[5120] (20480 words)
constexpr size_t WH_WC    = WF_WFRAG + 20480;                // f16[NGRAPH*2048*4]

// ---- LDS layout (bytes), total 151496 -> 1 block/CU ----
constexpr int S_H    = 0;        // f16 h[100][40] (cols 0..31 used)
constexpr int S_HP   = 8000;     // f16 hp[100][128] (col c -> d=c>>2,h=c&3), XOR-swizzled
constexpr int S_U    = 33600;    // f16 U[100][516]
constexpr int S_EH   = 136800;   // f32[100][4]
constexpr int S_ET   = 138400;   // f32[100][4]
constexpr int S_DEN  = 140000;   // f32[100][4]
constexpr int S_RA   = 141600;   // f32[16][4]
constexpr int S_ESG  = 141856;   // f32[4]
constexpr int S_AH   = 141872;   // f32[128] attn_h in hp-col order
constexpr int S_AT   = 142384;   // f32[128]
constexpr int S_MLDS = 142896;   // i32[2048] dst-sorted edge meta
constexpr int S_RP   = 151088;   // i32[102] rowptr
constexpr int S_TOTAL = 151496;
constexpr int UROW = 516;

typedef _Float16 f16x8 __attribute__((ext_vector_type(8)));
typedef _Float16 f16x2 __attribute__((ext_vector_type(2)));
typedef float f32x4 __attribute__((ext_vector_type(4)));

DI float lrelu(float x) { return x >= 0.f ? x : 0.2f * x; }
DI f16x8 u4_to_f16x8(uint4 u) { f16x8 r; __builtin_memcpy(&r, &u, 16); return r; }
DI f16x8 two_u2(uint2 a, uint2 b) { return u4_to_f16x8(make_uint4(a.x, a.y, b.x, b.y)); }
DI float h2f(unsigned short u) { __half hv; __builtin_memcpy(&hv, &u, 2); return __half2float(hv); }

// f32 += half2 . half2 via v_dot2_f32_f16
DI float fdot2u(unsigned a, unsigned b, float c) {
    f16x2 av, bv;
    __builtin_memcpy(&av, &a, 4);
    __builtin_memcpy(&bv, &b, 4);
    return __builtin_amdgcn_fdot2(av, bv, c, false);
}

// hp swizzle: half-index for (node n, col c); XOR bits 3..5 with n&7 (16B granularity)
DI int hpIdx(int n, int c) { return n * 128 + (c ^ ((n & 7) << 3)); }

// ---------------- merged prep: scatter-by-dst + prep folds + MFMA fragments ----------------
__global__ void k_prep(const int* __restrict__ src, const int* __restrict__ dst,
                       const int* __restrict__ rt, int* __restrict__ curs,
                       int* __restrict__ smeta,
                       const float* __restrict__ rel_table, const float* __restrict__ Wr,
                       const float* __restrict__ br, const float* __restrict__ We,
                       const float* __restrict__ be, const float* __restrict__ attn_r,
                       const float* __restrict__ attn_rs, const float* __restrict__ attn_s,
                       const float* __restrict__ W, float* __restrict__ prep,
                       uint4* __restrict__ wf) {
    __shared__ float wra[2][32][4];
    __shared__ float sbias[2][3][4];
    int bb = blockIdx.x, t = threadIdx.x;
    if (bb < SCAT_BLOCKS) {
        int e = bb * 256 + t;
        if (e >= EDGES) return;
        int s = src[e], d = dst[e], r = rt[e];
        int g = (unsigned)d / 100u;
        int pos = atomicAdd(&curs[d], 1);
        if (pos < CAP)
            smeta[((size_t)d << 6) + pos] = (s - g * 100) | (r << 7) | (e << 11);
        return;
    }
    int b = bb - SCAT_BLOCKS;
    if (b == 0) {
        {
            int l = t >> 7, k = (t >> 2) & 31, h = t & 3;
            float a = 0.f, b2 = 0.f, c = 0.f;
            for (int d2 = 0; d2 < 32; ++d2) {
                float w1 = Wr[(size_t)(l*32 + k)*128 + h*32 + d2];
                float w2 = We[(size_t)(l*32 + k)*128 + h*32 + d2];
                a  += w1 * attn_r [l*128 + h*32 + d2];
                b2 += w1 * attn_rs[l*128 + h*32 + d2];
                c  += w2 * attn_s [l*128 + h*32 + d2];
            }
            wra[l][k][h] = a;
            prep[128 + (l*32 + k)*4 + h] = b2;
            prep[384 + (l*32 + k)*4 + h] = c;
        }
        if (t < 24) {
            int l = t / 12, which = (t % 12) / 4, h = t % 4;
            const float* bp = (which == 2) ? be : br;
            const float* ap = (which == 0) ? attn_r : (which == 1 ? attn_rs : attn_s);
            float s = 0.f;
            for (int d2 = 0; d2 < 32; ++d2) s += bp[l*128 + h*32 + d2] * ap[l*128 + h*32 + d2];
            sbias[l][which][h] = s;
        }
        __syncthreads();
        if (t < 128) {
            int l = t >> 6, r = (t >> 2) & 15, h = t & 3;
            float s = sbias[l][0][h];
            for (int k = 0; k < 32; ++k) s += rel_table[r*32 + k] * wra[l][k][h];
            prep[(l*16 + r)*4 + h] = s;
        }
        if (t < 8) {
            int l = t >> 2, h = t & 3;
            prep[640 + l*4 + h] = sbias[l][1][h];
            prep[648 + l*4 + h] = sbias[l][2][h];
        }
    } else if (b <= 16) {
        // W fragments (f16): wf[((l*16+rel)*2+Nt)*64 + ln]
        int fi = (b - 1) * 256 + t;
        int ln = fi & 63, Nt = (fi >> 6) & 1, rel = (fi >> 7) & 15, l = fi >> 11;
        int j = Nt*16 + (ln & 15), k0 = (ln >> 4) << 3;
        unsigned short fr[8];
        #pragma unroll
        for (int i = 0; i < 8; ++i) {
            __half hv = __float2half(W[(((size_t)l*16 + rel)*32 + k0 + i)*32 + j]);
            __builtin_memcpy(&fr[i], &hv, 2);
        }
        uint4 o;
        o.x = fr[0] | ((unsigned)fr[1] << 16);
        o.y = fr[2] | ((unsigned)fr[3] << 16);
        o.z = fr[4] | ((unsigned)fr[5] << 16);
        o.w = fr[6] | ((unsigned)fr[7] << 16);
        wf[fi] = o;
    } else {
        // We fragments (f16, column-permuted): col c -> phys (c&3)*32+(c>>2)
        int fi = (b - 17) * 256 + t;
        int ln = fi & 63, Nt = (fi >> 6) & 7, l = fi >> 9;
        int c = Nt*16 + (ln & 15);
        int phys = (c & 3)*32 + (c >> 2);
        int k0 = (ln >> 4) << 3;
        unsigned short fr[8];
        #pragma unroll
        for (int i = 0; i < 8; ++i) {
            __half hv = __float2half(We[(size_t)l*4096 + (k0 + i)*128 + phys]);
            __builtin_memcpy(&fr[i], &hv, 2);
        }
        uint4 o;
        o.x = fr[0] | ((unsigned)fr[1] << 16);
        o.y = fr[2] | ((unsigned)fr[3] << 16);
        o.z = fr[4] | ((unsigned)fr[5] << 16);
        o.w = fr[6] | ((unsigned)fr[7] << 16);
        wf[4096 + fi] = o;
    }
}

// ---------------- fused per-graph forward: owner-computes, zero LDS atomics ----------------
__global__ void __launch_bounds__(1024, 1)
k_fused(const float* __restrict__ state, const float* __restrict__ rw,
        const float* __restrict__ code_emb, const float* __restrict__ h_bias,
        const float* __restrict__ be, const float* __restrict__ attn_h,
        const float* __restrict__ attn_t, const int* __restrict__ node_ids,
        const int* __restrict__ curs, const int* __restrict__ smeta,
        const float* __restrict__ prep, const uint4* __restrict__ wf,
        unsigned short* __restrict__ wc,
        float* __restrict__ xout, float* __restrict__ relOut, float* __restrict__ edgeOut) {
    extern __shared__ char smem[];
    __half* hH  = (__half*)(smem + S_H);
    __half* hpH = (__half*)(smem + S_HP);
    __half* Uh  = (__half*)(smem + S_U);
    float* ehp  = (float*)(smem + S_EH);
    float* etp  = (float*)(smem + S_ET);
    float* denp = (float*)(smem + S_DEN);
    float* rap  = (float*)(smem + S_RA);
    float* esgp = (float*)(smem + S_ESG);
    float* sAH  = (float*)(smem + S_AH);
    float* sAT  = (float*)(smem + S_AT);
    int*   mlds = (int*)(smem + S_MLDS);
    int*   rp   = (int*)(smem + S_RP);
    const uint4* wfe = wf + 4096;

    const int g = blockIdx.x;
    const int t = threadIdx.x;
    const int lane = t & 63, w = t >> 6;          // 16 waves
    const int ln15 = lane & 15, q = lane >> 4, q8 = q << 3;
    const int MtA = w % 7, NtA = w / 7;
    const bool hasT = (w < 14);
    const int cg = w >> 1;
    const int colc = cg * 16 + ln15;
    const int physc = (colc & 3) * 32 + (colc >> 2);
    const int Mt0 = (w & 1) ? 4 : 0;
    const int Mt1 = (w & 1) ? 7 : 4;

    unsigned short* wcg = wc + ((size_t)g << 13);     // 2048 edges x 4 halves
    const uint2* wcu = (const uint2*)wcg;

    // P0: h0 = code_emb[node_ids]; rowptr scan; CSR stage
    for (int i = t; i < 1600; i += 1024) {
        int n = i >> 4, dp = i & 15;
        int id = node_ids[g * 100 + n];
        float2 v = *(const float2*)&code_emb[(size_t)id * 32 + dp * 2];
        *(__half2*)&hH[n * 40 + dp * 2] = __floats2half2_rn(v.x, v.y);
    }
    if (t < 100) { int c = curs[g * 100 + t]; rp[t + 1] = c < CAP ? c : CAP; }
    if (t == 0) rp[0] = 0;
    __syncthreads();
    for (int o = 1; o < 128; o <<= 1) {
        int v = 0;
        if (t <= 100 && t >= o) v = rp[t - o];
        __syncthreads();
        if (t <= 100 && t >= o) rp[t] += v;
        __syncthreads();
    }
    for (int i = t; i < 100 * CAP; i += 1024) {
        int bin = i >> 6, pos = i & 63;
        int lo = rp[bin], cnt = rp[bin + 1] - lo;
        if (pos < cnt)
            mlds[lo + pos] = smeta[(((size_t)(g * 100 + bin)) << 6) + pos];
    }

    for (int l = 0; l < 2; ++l) {
        __syncthreads();   // B0: h/CSR ready, U free

        // ---- X1: zero U; stage sAH/sAT; MFMA hp = h@We + be; P1 rel-att ----
        for (int i = t; i < 6450; i += 1024) ((uint4*)(smem + S_U))[i] = make_uint4(0, 0, 0, 0);
        if (t < 128) {
            sAH[t] = attn_h[l * 128 + (t & 3) * 32 + (t >> 2)];
            sAT[t] = attn_t[l * 128 + (t & 3) * 32 + (t >> 2)];
        }
        {
            uint4 bwe = wfe[(l * 8 + cg) * 64 + lane];
            f16x8 bw = u4_to_f16x8(bwe);
            float beC = be[l * 128 + physc];
            f32x4 z = {0.f, 0.f, 0.f, 0.f};
            for (int Mt = Mt0; Mt < Mt1; ++Mt) {
                const __half* hr = hH + (Mt * 16 + ln15) * 40 + q8;
                f32x4 pc = __builtin_amdgcn_mfma_f32_16x16x32_f16(
                    two_u2(*(const uint2*)hr, *(const uint2*)(hr + 4)), bw, z, 0, 0, 0);
                #pragma unroll
                for (int i = 0; i < 4; ++i) {
                    int n = Mt * 16 + q * 4 + i;
                    if (n < 100) hpH[hpIdx(n, colc)] = __float2half(pc[i] + beC);
                }
            }
        }
        {   // P1: relation attention (all waves redundantly; benign identical writes)
            int k32 = lane & 31;
            float sG = state[g * 32 + k32];
            float4 frs = *(const float4*)&prep[128 + l * 128 + k32 * 4];
            float4 fes = *(const float4*)&prep[384 + l * 128 + k32 * 4];
            float p0 = sG * frs.x, p1 = sG * frs.y, p2 = sG * frs.z, p3 = sG * frs.w;
            float q0 = sG * fes.x, q1 = sG * fes.y, q2 = sG * fes.z, q3 = sG * fes.w;
            #pragma unroll
            for (int m = 1; m < 32; m <<= 1) {
                p0 += __shfl_xor(p0, m); p1 += __shfl_xor(p1, m);
                p2 += __shfl_xor(p2, m); p3 += __shfl_xor(p3, m);
                q0 += __shfl_xor(q0, m); q1 += __shfl_xor(q1, m);
                q2 += __shfl_xor(q2, m); q3 += __shfl_xor(q3, m);
            }
            int h = lane & 3;
            float esh  = (h & 2) ? ((h & 1) ? p3 : p2) : ((h & 1) ? p1 : p0);
            float esgh = (h & 2) ? ((h & 1) ? q3 : q2) : ((h & 1) ? q1 : q0);
            esh  += prep[640 + l * 4 + h];
            esgh += prep[648 + l * 4 + h];
            if (lane < 4) esgp[lane] = esgh;
            float er = prep[l * 64 + lane];
            float ex = __expf(lrelu(er + esh));
            float s = ex;
            s += __shfl_xor(s, 4); s += __shfl_xor(s, 8);
            s += __shfl_xor(s, 16); s += __shfl_xor(s, 32);
            rap[lane] = ex / s;
        }
        __syncthreads();   // B1: hp/sAH/sAT/rap/esg ready, U zeroed

        // ---- A0: eh/et per src node (owner = s; no atomics) ----
        if (t < 100) {
            int s = t;
            int sw = (s & 7) << 3;
            float eh[4] = {0, 0, 0, 0}, et[4] = {0, 0, 0, 0};
            #pragma unroll 4
            for (int i = 0; i < 16; ++i) {
                uint4 hv = *(const uint4*)&hpH[s * 128 + ((i * 8) ^ sw)];
                unsigned short hu[8];
                __builtin_memcpy(hu, &hv, 16);
                #pragma unroll
                for (int k = 0; k < 8; ++k) {
                    float f = h2f(hu[k]);
                    eh[k & 3] += f * sAH[i * 8 + k];
                    et[k & 3] += f * sAT[i * 8 + k];
                }
            }
            *(float4*)&ehp[s * 4] = make_float4(eh[0], eh[1], eh[2], eh[3]);
            *(float4*)&etp[s * 4] = make_float4(et[0], et[1], et[2], et[3]);
        }
        __syncthreads();   // B1b: eh/et ready

        // ---- A: den per (dst, head); then write packed coefficients to global wc ----
        if (t < 400) {
            int d = t >> 2, h = t & 3;
            int lo = rp[d], hi = rp[d + 1];
            float etd = etp[d * 4 + h] + esgp[h];
            float den = 0.f;
            for (int e = lo; e < hi; ++e) {
                int m = mlds[e];
                den += __expf(lrelu(ehp[(m & 127) * 4 + h] + etd));
            }
            denp[d * 4 + h] = den;
            float inv = 1.f / den;
            bool wAtt = (l == 1);
            for (int e = lo; e < hi; ++e) {
                int m = mlds[e];
                int r = (m >> 7) & 15;
                float a = __expf(lrelu(ehp[(m & 127) * 4 + h] + etd)) * inv;
                __half ch = __float2half(a * rap[r * 4 + h]);
                __builtin_memcpy(&wcg[e * 4 + h], &ch, 2);
                if (wAtt) {
                    int oe = (m >> 11) & 0xFFFFF;
                    edgeOut[(size_t)oe * 4 + h] = a;
                    relOut[(size_t)oe * 4 + h] = rap[r * 4 + h];
                }
            }
        }
        __syncthreads();   // B2: den + wc ready (vmcnt drained by barrier)

        // ---- B: U accumulation per (dst, dim-quad) (coef from wc; fdot2 + pk_add) ----
        if (t < 800) {
            int d = t >> 3, j = t & 7;          // dims [j*4, j*4+4)
            int lo = rp[d], hi = rp[d + 1];
            for (int e = lo; e < hi; ++e) {
                int m = mlds[e];
                int s = m & 127, r = (m >> 7) & 15;
                uint2 cc = wcu[e];
                int sw = (s & 7) << 3;
                uint4 hv0 = *(const uint4*)&hpH[s * 128 + ((j * 16) ^ sw)];
                uint4 hv1 = *(const uint4*)&hpH[s * 128 + ((j * 16 + 8) ^ sw)];
                float v0 = fdot2u(cc.x, hv0.x, fdot2u(cc.y, hv0.y, 0.f));
                float v1 = fdot2u(cc.x, hv0.z, fdot2u(cc.y, hv0.w, 0.f));
                float v2 = fdot2u(cc.x, hv1.x, fdot2u(cc.y, hv1.y, 0.f));
                float v3 = fdot2u(cc.x, hv1.z, fdot2u(cc.y, hv1.w, 0.f));
                __half2 v01 = __floats2half2_rn(v0, v1);
                __half2 v23 = __floats2half2_rn(v2, v3);
                __half2* up = (__half2*)(Uh + d * UROW + r * 32 + j * 4);
                up[0] = __hadd2(up[0], v01);
                up[1] = __hadd2(up[1], v23);
            }
        }
        __syncthreads();   // B3: U complete

        // ---- P7: 16-relation MFMA chain (waves 0..13) ----
        f32x4 accA = {0.f, 0.f, 0.f, 0.f};
        if (hasT) {
            #pragma unroll 4
            for (int rel = 0; rel < 16; ++rel) {
                uint4 bAu = wf[((l * 16 + rel) * 2 + NtA) * 64 + lane];
                const __half* up = Uh + (MtA * 16 + ln15) * UROW + rel * 32 + q8;
                f16x8 af = two_u2(*(const uint2*)up, *(const uint2*)(up + 4));
                accA = __builtin_amdgcn_mfma_f32_16x16x32_f16(af, u4_to_f16x8(bAu), accA, 0, 0, 0);
            }
        }
        // P8: h = relu(0.5*(agg+bias) + 0.5*h)
        if (hasT) {
            int dcol = NtA * 16 + ln15;
            float bias = h_bias[l * 32 + dcol];
            #pragma unroll
            for (int i = 0; i < 4; ++i) {
                int n = MtA * 16 + q * 4 + i;
                if (n < 100) {
                    float hold = __half2float(hH[n * 40 + dcol]);
                    float hn = fmaxf(0.f, 0.5f * (accA[i] + bias) + 0.5f * hold);
                    hH[n * 40 + dcol] = __float2half(hn);
                }
            }
        }
    }
    __syncthreads();   // h final

    // P9: readout x[g] = sum_n h[n] * rw[n]   (red buffer reuses U region)
    float* redp = (float*)(smem + S_U);
    {
        int part = t >> 5, d = t & 31;
        float acc = 0.f;
        for (int n = part; n < 100; n += 32)
            acc += __half2float(hH[n * 40 + d]) * rw[g * 100 + n];
        redp[part * 32 + d] = acc;
    }
    __syncthreads();
    if (t < 32) {
        float s = 0.f;
        #pragma unroll
        for (int p = 0; p < 32; ++p) s += redp[p * 32 + t];
        xout[g * 32 + t] = s;
    }
}

extern "C" void kernel_launch(void* const* d_in, const int* in_sizes, int n_in,
                              void* d_out, int out_size, void* d_ws, size_t ws_size,
                              hipStream_t stream) {
    const float* state     = (const float*)d_in[0];
    const float* rw        = (const float*)d_in[1];
    const float* code_emb  = (const float*)d_in[2];
    const float* rel_table = (const float*)d_in[3];
    const float* W         = (const float*)d_in[4];
    const float* h_bias    = (const float*)d_in[5];
    const float* Wr        = (const float*)d_in[6];
    const float* br        = (const float*)d_in[7];
    const float* We        = (const float*)d_in[8];
    const float* be        = (const float*)d_in[9];
    const float* attn_h    = (const float*)d_in[10];
    const float* attn_t    = (const float*)d_in[11];
    const float* attn_s    = (const float*)d_in[12];
    const float* attn_r    = (const float*)d_in[13];
    const float* attn_rs   = (const float*)d_in[14];
    const int* node_ids    = (const int*)d_in[15];
    const int* src         = (const int*)d_in[16];
    const int* dst         = (const int*)d_in[17];
    const int* rtype       = (const int*)d_in[18];

    float* out = (float*)d_out;
    float* xout = out;
    float* relOut = out + (size_t)NGRAPH * 32;
    float* edgeOut = relOut + (size_t)EDGES * 4;

    int* wsi = (int*)d_ws;
    float* wsf = (float*)d_ws;
    int* curs   = wsi + WI_CURS;
    int* smeta  = wsi + WI_SMETA;
    float* prep = wsf + WF_PREP;
    uint4* wfrag = (uint4*)(wsf + WF_WFRAG);
    unsigned short* wc = (unsigned short*)(wsf + WH_WC);

    (void)hipMemsetAsync(curs, 0, NNODE * sizeof(int), stream);
    k_prep<<<SCAT_BLOCKS + 21, 256, 0, stream>>>(src, dst, rtype, curs, smeta,
                                                 rel_table, Wr, br, We, be,
                                                 attn_r, attn_rs, attn_s, W, prep, wfrag);

    (void)hipFuncSetAttribute((const void*)k_fused, hipFuncAttributeMaxDynamicSharedMemorySize, S_TOTAL);
    k_fused<<<NGRAPH, 1024, S_TOTAL, stream>>>(state, rw, code_emb, h_bias, be,
                                               attn_h, attn_t, node_ids, curs, smeta,
                                               prep, wfrag, wc, xout, relOut, edgeOut);
}